// Round 9
// baseline (626.727 us; speedup 1.0000x reference)
//
#include <hip/hip_runtime.h>
#include <cfloat>

// Problem constants: B=32, C=64, H=W=32, V=4096, SN=6, RESI=0.5, BETA=0.25
#define N_ELEM 2097152   // 32*64*32*32
#define TAU 2.0e-2f      // approx-score decision margin (>> worst-case split-bf16 error ~5e-4)

typedef short s16x8 __attribute__((ext_vector_type(8)));
typedef float f32x4 __attribute__((ext_vector_type(4)));

__device__ __forceinline__ unsigned short f2bf(float v) {   // RNE float->bf16 bits
    unsigned u = __float_as_uint(v);
    u += 0x7FFFu + ((u >> 16) & 1u);
    return (unsigned short)(u >> 16);
}
__device__ __forceinline__ float bf2f(unsigned short h) {
    return __uint_as_float(((unsigned)h) << 16);
}

__device__ __forceinline__ float blockReduceSum(float v) {
    __shared__ float red[4];
    #pragma unroll
    for (int off = 32; off; off >>= 1) v += __shfl_down(v, off, 64);
    int wid = threadIdx.x >> 6, lane = threadIdx.x & 63;
    if (lane == 0) red[wid] = v;
    __syncthreads();
    float r = 0.f;
    if (threadIdx.x == 0) {
        int nw = ((int)blockDim.x + 63) >> 6;
        for (int w = 0; w < nw; ++w) r += red[w];
    }
    __syncthreads();
    return r;
}

// codebook prep: half squared norms (f32) + NEGATED bf16 hi/lo planes (C-init trick:
// acc = q + sum(-e * r) = q - dot => min-orientation top-2 logic unchanged)
__global__ void k_embprep(const float* __restrict__ e, float* __restrict__ hesq,
                          unsigned short* __restrict__ ehiN, unsigned short* __restrict__ eloN) {
    int v = blockIdx.x * 256 + threadIdx.x;
    if (v >= 4096) return;
    const float4* r = (const float4*)(e + (size_t)v * 64);
    float s = 0.f;
    #pragma unroll
    for (int i = 0; i < 16; ++i) {
        float4 a = r[i];
        s += a.x * a.x + a.y * a.y + a.z * a.z + a.w * a.w;
    }
    hesq[v] = 0.5f * s;
    for (int i = 0; i < 64; ++i) {
        float x = e[(size_t)v * 64 + i];
        unsigned short h = f2bf(x);
        ehiN[(size_t)v * 64 + i] = h ^ 0x8000u;
        eloN[(size_t)v * 64 + i] = f2bf(x - bf2f(h)) ^ 0x8000u;
    }
}

// modulated conv weights -> MFMA layout [k][tap][co][ci] bf16 hi/lo
__global__ void k_wmod(const float* __restrict__ w, const float* __restrict__ fcw,
                       const float* __restrict__ fcb,
                       unsigned short* __restrict__ wh, unsigned short* __restrict__ wl) {
    int i = blockIdx.x * 256 + threadIdx.x;
    if (i >= 4 * 64 * 64 * 9) return;
    int k = i / (64 * 64 * 9);
    int r = i % (64 * 64 * 9);
    int oi = r / 9;            // co*64 + ci
    int t = r % 9;
    int co = oi >> 6, ci = oi & 63;
    float cond = fcw[k * 4096 + oi] * 6.0f + fcb[k * 4096 + oi];
    float v = w[i] * (1.0f + cond);
    size_t o = ((size_t)(k * 9 + t) * 64 + co) * 64 + ci;
    unsigned short h = f2bf(v);
    wh[o] = h;
    wl[o] = f2bf(v - bf2f(h));
}

// ---- plane-parallel downsample: one block per (b,c), coalesced reads, LDS reduce ----
__global__ __launch_bounds__(256) void k_down_plane(
        const float* __restrict__ f, const float* __restrict__ fhat,
        float* __restrict__ restnc, unsigned short* __restrict__ dhi,
        unsigned short* __restrict__ dlo, float* __restrict__ cmpPrev, int pn) {
    __shared__ float hs[32][16];   // per-(row, x-pair) partial sums
    __shared__ float cr[32][16];   // per-(row, patch-col) sums
    __shared__ float pm[256];      // patch means (pn*pn <= 256 for pn<=16)
    int bc = blockIdx.x;           // b*64 + c
    int c = bc & 63, b = bc >> 6;
    int t = threadIdx.x;
    const float4* fp = (const float4*)(f + (size_t)bc * 1024);
    const float4* hp = (const float4*)(fhat + (size_t)bc * 1024);
    float4 a = fp[t], q = hp[t];
    int r = t >> 3, c4 = t & 7;
    hs[r][c4 * 2]     = (a.x - q.x) + (a.y - q.y);
    hs[r][c4 * 2 + 1] = (a.z - q.z) + (a.w - q.w);
    __syncthreads();
    int cpp = 16 / pn;             // x-pairs per patch column
    for (int i = t; i < 32 * pn; i += 256) {
        int rr = i / pn, px = i % pn;
        float s = 0.f;
        for (int j = 0; j < cpp; ++j) s += hs[rr][px * cpp + j];
        cr[rr][px] = s;
    }
    __syncthreads();
    int s_ = 32 / pn;
    float inv = 1.0f / (float)(s_ * s_);
    for (int p = t; p < pn * pn; p += 256) {
        int py = p / pn, px = p % pn;
        float s = 0.f;
        for (int j = 0; j < s_; ++j) s += cr[py * s_ + j][px];
        float m = s * inv;
        pm[p] = m;
        int n = (b * pn + py) * pn + px;
        size_t o = (size_t)n * 64 + c;
        unsigned short h = f2bf(m);
        restnc[o] = m;
        dhi[o] = h;
        dlo[o] = f2bf(m - bf2f(h));
    }
    if (pn >= 2) {
        __syncthreads();
        int pnp = pn >> 1;
        float m2 = 0.f;
        for (int p = t; p < pnp * pnp; p += 256) {
            int py = p / pnp, px = p % pnp;
            float mm = 0.25f * (pm[(2 * py) * pn + 2 * px] + pm[(2 * py) * pn + 2 * px + 1]
                              + pm[(2 * py + 1) * pn + 2 * px] + pm[(2 * py + 1) * pn + 2 * px + 1]);
            m2 += mm * mm;
        }
        m2 = blockReduceSum(m2);
        if (t == 0) cmpPrev[blockIdx.x] = m2;
    }
}

// NCHW plane-major [64][1024] per b -> [N][64] f32 + bf16 hi/lo of (f - fhat)  (si=5)
// + fused commit partial for si=4: 2x2 means of the diff -> cmp[bx*16 + by] (512 slots).
__global__ void k_trans_nc(const float* __restrict__ A, const float* __restrict__ Bt,
                           float* __restrict__ dst,
                           unsigned short* __restrict__ dhi, unsigned short* __restrict__ dlo,
                           float* __restrict__ cmp) {
    __shared__ float t[64][65];
    int b = blockIdx.x;
    int p0 = blockIdx.y * 64;
    int lane = threadIdx.x & 63, r4 = threadIdx.x >> 6;
    #pragma unroll
    for (int i = 0; i < 16; ++i) {
        int c = i * 4 + r4;
        size_t g = ((size_t)b * 64 + c) * 1024 + p0 + lane;
        t[c][lane] = A[g] - Bt[g];
    }
    __syncthreads();
    #pragma unroll
    for (int i = 0; i < 16; ++i) {
        int p = i * 4 + r4;
        size_t o = ((size_t)(b * 1024 + p0 + p)) * 64 + lane;
        float v = t[lane][p];
        unsigned short h = f2bf(v);
        dst[o] = v;
        dhi[o] = h;
        dlo[o] = f2bf(v - bf2f(h));
    }
    // commit si=4 partial: 64 c x 16 px 2x2-means
    float m2s = 0.f;
    for (int i = threadIdx.x; i < 1024; i += 256) {
        int c = i & 63, px = i >> 6;
        float m = 0.25f * (t[c][2 * px] + t[c][2 * px + 1] + t[c][32 + 2 * px] + t[c][33 + 2 * px]);
        m2s += m * m;
    }
    m2s = blockReduceSum(m2s);
    if (threadIdx.x == 0) cmp[blockIdx.x * 16 + blockIdx.y] = m2s;
}

// ---- MFMA VQ scan: 64 points/wave (4 tiles), negated-code C-init, fast-path top-2 ----
// Fast path (gmin >= m1): m2' = min(gmin, m2) is EXACT (at most gmin can enter top-2).
// Slow path (rare): full group-2nd via sort network + argmin index with
// lower-index tie preference (matches np.argmin).
__global__ __launch_bounds__(256) void k_vq_mfma(
        const unsigned short* __restrict__ resthi, const unsigned short* __restrict__ restlo,
        const unsigned short* __restrict__ embhiN, const unsigned short* __restrict__ embloN,
        const float* __restrict__ hesq,
        float* __restrict__ m1v_, int* __restrict__ m1i_, float* __restrict__ m2v_,
        int N, int CPS) {
    __shared__ __align__(16) unsigned short lah[64 * 64];
    __shared__ __align__(16) unsigned short lal[64 * 64];
    __shared__ __align__(16) float lq[64];
    int tid = threadIdx.x;
    int lane = tid & 63, wv = tid >> 6;
    int split = blockIdx.y;
    int p0 = blockIdx.x * 256 + wv * 64;
    int cr = lane & 15, oct = lane >> 4;
    int ko8 = oct * 8;
    int sw = (cr & 7) << 4;

    s16x8 bh0[4], bh1[4], bl0[4], bl1[4];
    #pragma unroll
    for (int T = 0; T < 4; ++T) {
        int pt = min(p0 + T * 16 + cr, N - 1);
        const unsigned short* rh = resthi + (size_t)pt * 64;
        const unsigned short* rl = restlo + (size_t)pt * 64;
        bh0[T] = *(const s16x8*)(rh + ko8);
        bh1[T] = *(const s16x8*)(rh + 32 + ko8);
        bl0[T] = *(const s16x8*)(rl + ko8);
        bl1[T] = *(const s16x8*)(rl + 32 + ko8);
    }
    float m1v[4] = {FLT_MAX, FLT_MAX, FLT_MAX, FLT_MAX};
    float m2v[4] = {FLT_MAX, FLT_MAX, FLT_MAX, FLT_MAX};
    int m1i[4] = {0, 0, 0, 0};

    int cbeg = split * CPS;
    for (int oc = 0; oc < CPS; oc += 64) {
        int cb = cbeg + oc;
        __syncthreads();
        for (int t = tid; t < 512; t += 256) {
            int cc = t >> 3, part = t & 7;
            int bo = (cc * 128 + part * 16) ^ ((cc & 7) << 4);
            *(uint4*)((char*)lah + bo) = *(const uint4*)(embhiN + (size_t)(cb + cc) * 64 + part * 8);
            *(uint4*)((char*)lal + bo) = *(const uint4*)(embloN + (size_t)(cb + cc) * 64 + part * 8);
        }
        if (tid < 64) lq[tid] = hesq[cb + tid];
        __syncthreads();
        #pragma unroll
        for (int sub = 0; sub < 4; ++sub) {
            int rowb = (sub * 16 + cr) * 128;
            s16x8 ah0 = *(const s16x8*)((const char*)lah + ((rowb + ko8 * 2) ^ sw));
            s16x8 ah1 = *(const s16x8*)((const char*)lah + ((rowb + 64 + ko8 * 2) ^ sw));
            s16x8 al0 = *(const s16x8*)((const char*)lal + ((rowb + ko8 * 2) ^ sw));
            s16x8 al1 = *(const s16x8*)((const char*)lal + ((rowb + 64 + ko8 * 2) ^ sw));
            f32x4 q = *(const f32x4*)(lq + sub * 16 + oct * 4);
            int crow = cb + sub * 16 + oct * 4;
            #pragma unroll
            for (int T = 0; T < 4; ++T) {
                f32x4 a = q;
                a = __builtin_amdgcn_mfma_f32_16x16x32_bf16(ah0, bh0[T], a, 0, 0, 0);
                a = __builtin_amdgcn_mfma_f32_16x16x32_bf16(ah1, bh1[T], a, 0, 0, 0);
                a = __builtin_amdgcn_mfma_f32_16x16x32_bf16(ah0, bl0[T], a, 0, 0, 0);
                a = __builtin_amdgcn_mfma_f32_16x16x32_bf16(ah1, bl1[T], a, 0, 0, 0);
                a = __builtin_amdgcn_mfma_f32_16x16x32_bf16(al0, bh0[T], a, 0, 0, 0);
                a = __builtin_amdgcn_mfma_f32_16x16x32_bf16(al1, bh1[T], a, 0, 0, 0);
                float m01 = fminf(a[0], a[1]);
                float m23 = fminf(a[2], a[3]);
                float gmin = fminf(m01, m23);
                m2v[T] = fminf(gmin, m2v[T]);
                if (gmin < m1v[T]) {
                    float M01 = fmaxf(a[0], a[1]);
                    float M23 = fmaxf(a[2], a[3]);
                    float g2 = fminf(fmaxf(m01, m23), fminf(M01, M23));
                    int i01 = (a[1] < a[0]) ? crow + 1 : crow;
                    int i23 = (a[3] < a[2]) ? crow + 3 : crow + 2;
                    int gi = (m23 < m01) ? i23 : i01;
                    m2v[T] = fminf(m1v[T], g2);
                    m1v[T] = gmin;
                    m1i[T] = gi;
                }
            }
        }
    }
    #pragma unroll
    for (int T = 0; T < 4; ++T) {
        #pragma unroll
        for (int off = 16; off <= 32; off <<= 1) {
            float o1 = __shfl_xor(m1v[T], off, 64);
            int oi = __shfl_xor(m1i[T], off, 64);
            float o2 = __shfl_xor(m2v[T], off, 64);
            bool lt = o1 < m1v[T];
            m2v[T] = fminf(fmaxf(o1, m1v[T]), fminf(m2v[T], o2));
            m1v[T] = fminf(o1, m1v[T]);
            m1i[T] = lt ? oi : m1i[T];
        }
        if (oct == 0) {
            int pt = p0 + T * 16 + cr;
            if (pt < N) {
                size_t o = (size_t)split * N + pt;
                m1v_[o] = m1v[T]; m1i_[o] = m1i[T]; m2v_[o] = m2v[T];
            }
        }
    }
}

// merge split partials; init pmin; decide or flag for exact fallback
__global__ void k_vq_combine(const float* __restrict__ m1v_, const int* __restrict__ m1i_,
                             const float* __restrict__ m2v_,
                             int* __restrict__ idx, int* __restrict__ flag, int* __restrict__ count,
                             unsigned long long* __restrict__ pmin, int N, int SPLITS) {
    int n = blockIdx.x * 256 + threadIdx.x;
    if (n >= N) return;
    float a1v = m1v_[n], a2v = m2v_[n];
    int a1i = m1i_[n];
    for (int s = 1; s < SPLITS; ++s) {
        size_t o = (size_t)s * N + n;
        float b1v = m1v_[o], b2v = m2v_[o];
        int b1i = m1i_[o];
        bool lt = b1v < a1v;
        a2v = fminf(fmaxf(b1v, a1v), fminf(a2v, b2v));
        a1v = fminf(b1v, a1v);
        a1i = lt ? b1i : a1i;
    }
    idx[n] = a1i;
    pmin[n] = 0xFFFFFFFFFFFFFFFFull;
    if (a2v - a1v < TAU) {
        int p = atomicAdd(count, 1);
        flag[p] = n;
    }
}

// exact f32 rescan for flagged points (wave-level atomicMin)
__global__ __launch_bounds__(256) void k_vq_exact(
        const float* __restrict__ restnc, const float* __restrict__ embed,
        const float* __restrict__ hesq, const int* __restrict__ flag,
        const int* __restrict__ count, unsigned long long* __restrict__ pmin) {
    __shared__ float rs[32 * 64];
    int tid = threadIdx.x;
    int lane = tid & 63;
    int cnt = *count;
    int nb = (cnt + 31) >> 5;
    int ntask = nb * 16;
    for (int task = blockIdx.x; task < ntask; task += gridDim.x) {
        int batch = task >> 4, spl = task & 15;
        int lbase = batch << 5;
        int npts = min(32, cnt - lbase);
        __syncthreads();
        for (int i = tid; i < npts * 64; i += 256) {
            int li = i >> 6;
            rs[i] = restnc[(size_t)flag[lbase + li] * 64 + (i & 63)];
        }
        __syncthreads();
        int code = spl * 256 + tid;
        const float4* e4 = (const float4*)(embed + (size_t)code * 64);
        float4 e[16];
        #pragma unroll
        for (int i = 0; i < 16; ++i) e[i] = e4[i];
        float hq = hesq[code];
        for (int p = 0; p < npts; ++p) {
            const float4* r4 = (const float4*)(rs + p * 64);
            float d0 = 0.f, d1 = 0.f, d2 = 0.f, d3 = 0.f;
            #pragma unroll
            for (int i = 0; i < 16; i += 4) {
                float4 e0 = e[i], e1 = e[i + 1], e2 = e[i + 2], e3 = e[i + 3];
                d0 += e0.x * r4[i].x     + e0.y * r4[i].y     + e0.z * r4[i].z     + e0.w * r4[i].w;
                d1 += e1.x * r4[i + 1].x + e1.y * r4[i + 1].y + e1.z * r4[i + 1].z + e1.w * r4[i + 1].w;
                d2 += e2.x * r4[i + 2].x + e2.y * r4[i + 2].y + e2.z * r4[i + 2].z + e2.w * r4[i + 2].w;
                d3 += e3.x * r4[i + 3].x + e3.y * r4[i + 3].y + e3.z * r4[i + 3].z + e3.w * r4[i + 3].w;
            }
            float s = hq - ((d0 + d1) + (d2 + d3));
            unsigned u = __float_as_uint(s);
            u = (u & 0x80000000u) ? ~u : (u | 0x80000000u);
            unsigned long long pk = (((unsigned long long)u) << 32) | (unsigned)code;
            #pragma unroll
            for (int off = 32; off; off >>= 1) {
                unsigned long long o = __shfl_down(pk, off, 64);
                if (o < pk) pk = o;
            }
            if (lane == 0) atomicMin(pmin + flag[lbase + p], pk);
        }
    }
}

// fused gather + bilinear upsample (or identity for pn=32) -> NHWC bf16 hi/lo only
__global__ void k_up(const int* __restrict__ idx, const unsigned long long* __restrict__ pmin,
                     const float* __restrict__ embed,
                     unsigned short* __restrict__ huph, unsigned short* __restrict__ hupl,
                     int pn) {
    int i = blockIdx.x * 256 + threadIdx.x;
    if (i >= N_ELEM) return;
    int c = i & 63, x = (i >> 6) & 31, y = (i >> 11) & 31, b = i >> 16;
    float v;
    if (pn == 32) {
        int n = (b * 32 + y) * 32 + x;
        unsigned long long pv = pmin[n];
        int id = (pv != 0xFFFFFFFFFFFFFFFFull) ? (int)(pv & 0xFFFFFFFFull) : idx[n];
        v = embed[(size_t)id * 64 + c];
    } else {
        float scale = (float)pn * (1.0f / 32.0f);
        float sy = (y + 0.5f) * scale - 0.5f;
        float sx = (x + 0.5f) * scale - 0.5f;
        float fy0 = floorf(sy), fx0 = floorf(sx);
        float wy = sy - fy0, wx = sx - fx0;
        int y0 = max(0, min(pn - 1, (int)fy0));
        int y1 = max(0, min(pn - 1, (int)fy0 + 1));
        int x0 = max(0, min(pn - 1, (int)fx0));
        int x1 = max(0, min(pn - 1, (int)fx0 + 1));
        int nb_ = b * pn * pn;
        int n00 = nb_ + y0 * pn + x0, n01 = nb_ + y0 * pn + x1;
        int n10 = nb_ + y1 * pn + x0, n11 = nb_ + y1 * pn + x1;
        unsigned long long p00 = pmin[n00], p01 = pmin[n01], p10 = pmin[n10], p11 = pmin[n11];
        int i00 = (p00 != 0xFFFFFFFFFFFFFFFFull) ? (int)(p00 & 0xFFFFFFFFull) : idx[n00];
        int i01 = (p01 != 0xFFFFFFFFFFFFFFFFull) ? (int)(p01 & 0xFFFFFFFFull) : idx[n01];
        int i10 = (p10 != 0xFFFFFFFFFFFFFFFFull) ? (int)(p10 & 0xFFFFFFFFull) : idx[n10];
        int i11 = (p11 != 0xFFFFFFFFFFFFFFFFull) ? (int)(p11 & 0xFFFFFFFFull) : idx[n11];
        float v00 = embed[(size_t)i00 * 64 + c];
        float v01 = embed[(size_t)i01 * 64 + c];
        float v10 = embed[(size_t)i10 * 64 + c];
        float v11 = embed[(size_t)i11 * 64 + c];
        v = (1.f - wy) * ((1.f - wx) * v00 + wx * v01) + wy * ((1.f - wx) * v10 + wx * v11);
    }
    unsigned short h = f2bf(v);
    huph[i] = h;
    hupl[i] = f2bf(v - bf2f(h));
}

// ---- MFMA 3x3 conv: 2 co-tiles x 4 px-tiles per wave, 3-term split,
// blend operand h = hi+lo read back from LDS tile.
__global__ __launch_bounds__(256) void k_conv_mfma(
        const unsigned short* __restrict__ huph, const unsigned short* __restrict__ hupl,
        const unsigned short* __restrict__ wh, const unsigned short* __restrict__ wl,
        const float* __restrict__ bias, const float* __restrict__ f_in,
        float* __restrict__ f_hat, float* __restrict__ vq_part) {
    __shared__ __align__(16) unsigned short Xh[6 * 34 * 64];
    __shared__ __align__(16) unsigned short Xl[6 * 34 * 64];
    int b = blockIdx.x, rg = blockIdx.y;
    int y0 = rg * 4;
    int tid = threadIdx.x;
    int lane = tid & 63, wv = tid >> 6;
    int coh = (wv & 1) * 32;       // co half
    int ph  = (wv >> 1) * 4;       // px-tile base (4 tiles = 2 rows)
    int cr = lane & 15, oct = lane >> 4;

    for (int q = tid; q < 6 * 34 * 8; q += 256) {
        int pl = q >> 3, o8 = q & 7;
        int lr = pl / 34, lc = pl % 34;
        int gy = y0 + lr - 1, gx = lc - 1;
        int bo = (pl * 128 + o8 * 16) ^ ((lc & 7) << 4);
        uint4 vh = {0, 0, 0, 0}, vl = {0, 0, 0, 0};
        if (gy >= 0 && gy < 32 && gx >= 0 && gx < 32) {
            size_t g = (((size_t)(b * 32 + gy)) * 32 + gx) * 64 + o8 * 8;
            vh = *(const uint4*)(huph + g);
            vl = *(const uint4*)(hupl + g);
        }
        *(uint4*)((char*)Xh + bo) = vh;
        *(uint4*)((char*)Xl + bo) = vl;
    }
    __syncthreads();

    f32x4 acc[2][4];
    #pragma unroll
    for (int ct = 0; ct < 2; ++ct)
        #pragma unroll
        for (int pp = 0; pp < 4; ++pp) acc[ct][pp] = (f32x4){0.f, 0.f, 0.f, 0.f};

    for (int t = 0; t < 9; ++t) {
        int dy = t / 3, dx = t % 3;
        #pragma unroll
        for (int cc = 0; cc < 2; ++cc) {
            size_t wo0 = ((size_t)t * 64 + coh + cr) * 64 + cc * 32 + oct * 8;
            size_t wo1 = ((size_t)t * 64 + coh + 16 + cr) * 64 + cc * 32 + oct * 8;
            s16x8 Ah0 = *(const s16x8*)(wh + wo0);
            s16x8 Al0 = *(const s16x8*)(wl + wo0);
            s16x8 Ah1 = *(const s16x8*)(wh + wo1);
            s16x8 Al1 = *(const s16x8*)(wl + wo1);
            #pragma unroll
            for (int pp = 0; pp < 4; ++pp) {
                int px = (ph + pp) * 16 + cr;
                int lr = (px >> 5) + dy;
                int lc = (px & 31) + dx;
                int bo = ((lr * 34 + lc) * 128 + cc * 64 + oct * 16) ^ ((lc & 7) << 4);
                s16x8 Bh = *(const s16x8*)((const char*)Xh + bo);
                s16x8 Bl = *(const s16x8*)((const char*)Xl + bo);
                acc[0][pp] = __builtin_amdgcn_mfma_f32_16x16x32_bf16(Ah0, Bh, acc[0][pp], 0, 0, 0);
                acc[0][pp] = __builtin_amdgcn_mfma_f32_16x16x32_bf16(Ah0, Bl, acc[0][pp], 0, 0, 0);
                acc[0][pp] = __builtin_amdgcn_mfma_f32_16x16x32_bf16(Al0, Bh, acc[0][pp], 0, 0, 0);
                acc[1][pp] = __builtin_amdgcn_mfma_f32_16x16x32_bf16(Ah1, Bh, acc[1][pp], 0, 0, 0);
                acc[1][pp] = __builtin_amdgcn_mfma_f32_16x16x32_bf16(Ah1, Bl, acc[1][pp], 0, 0, 0);
                acc[1][pp] = __builtin_amdgcn_mfma_f32_16x16x32_bf16(Al1, Bh, acc[1][pp], 0, 0, 0);
            }
        }
    }

    // epilogue: D row (co-in-tile) = oct*4 + r, D col (px-in-tile) = cr
    float local = 0.f;
    #pragma unroll
    for (int ct = 0; ct < 2; ++ct) {
        int cbase = coh + ct * 16 + oct * 4;
        #pragma unroll
        for (int pp = 0; pp < 4; ++pp) {
            int px = (ph + pp) * 16 + cr;
            int y = y0 + (px >> 5), x = px & 31;
            int lr = (px >> 5) + 1, lc = (px & 31) + 1;
            int bo = ((lr * 34 + lc) * 128 + cbase * 2) ^ ((lc & 7) << 4);
            ushort4 hvh = *(const ushort4*)((const char*)Xh + bo);
            ushort4 hvl = *(const ushort4*)((const char*)Xl + bo);
            #pragma unroll
            for (int r = 0; r < 4; ++r) {
                int co = cbase + r;
                unsigned short uh = (r == 0) ? hvh.x : (r == 1) ? hvh.y : (r == 2) ? hvh.z : hvh.w;
                unsigned short ul = (r == 0) ? hvl.x : (r == 1) ? hvl.y : (r == 2) ? hvl.z : hvl.w;
                float hv = bf2f(uh) + bf2f(ul);
                float hconv = acc[ct][pp][r] + bias[co];
                float hout = 0.5f * hv + 0.5f * hconv;
                size_t o = (((size_t)(b * 64 + co)) * 32 + y) * 32 + x;
                float fh = f_hat[o] + hout;
                f_hat[o] = fh;
                float d = fh - f_in[o];
                local += d * d;
            }
        }
    }
    local = blockReduceSum(local);
    if (tid == 0) vq_part[b * 8 + rg] = local;
}

// final: vq losses from vqp (6x256), commit from cmpP (per-scale slot counts) + vq5 identity
__global__ void k_final(const float* __restrict__ vqp, const float* __restrict__ cmpP,
                        float* __restrict__ out) {
    const int pn2s[5] = {1, 4, 16, 64, 256};
    const int slots[5] = {2048, 2048, 2048, 2048, 512};
    __shared__ float commit_s;
    if (threadIdx.x == 0) commit_s = 0.f;
    __syncthreads();
    for (int si = 0; si < 6; ++si) {
        float l = vqp[si * 256 + threadIdx.x];
        l = blockReduceSum(l);
        if (threadIdx.x == 0) {
            float vl = l / (float)N_ELEM;
            out[N_ELEM + si] = vl;
            if (si == 5) commit_s += vl * 0.25f;   // commit(si=5) == vq loss 5
        }
        if (si < 5) {
            float csum = 0.f;
            for (int i = threadIdx.x; i < slots[si]; i += 256) csum += cmpP[si * 2048 + i];
            csum = blockReduceSum(csum);
            if (threadIdx.x == 0) commit_s += csum / (float)(2048 * pn2s[si]) * 0.25f;
        }
    }
    __syncthreads();
    if (threadIdx.x == 0) out[N_ELEM + 6] = commit_s / 6.0f;
}

extern "C" void kernel_launch(void* const* d_in, const int* in_sizes, int n_in,
                              void* d_out, int out_size, void* d_ws, size_t ws_size,
                              hipStream_t stream) {
    const float* f     = (const float*)d_in[0];
    const float* embed = (const float*)d_in[1];
    const float* convw = (const float*)d_in[2];
    const float* convb = (const float*)d_in[3];
    const float* fcw   = (const float*)d_in[4];
    const float* fcb   = (const float*)d_in[5];
    float* out = (float*)d_out;        // f_hat lives in out[0..N_ELEM)
    float* ws  = (float*)d_ws;

    float* restnc = ws + 2097152;                               // 2097152
    unsigned short* resthi = (unsigned short*)(ws + 4194304);   // 2M u16 (alias huph)
    unsigned short* restlo = (unsigned short*)(ws + 5242880);   // 2M u16 (alias hupl)
    unsigned short* huph   = resthi;
    unsigned short* hupl   = restlo;
    unsigned short* embhiN = (unsigned short*)(ws + 6291456);   // 262144 u16
    unsigned short* embloN = (unsigned short*)(ws + 6422528);   // 262144 u16
    unsigned short* wmodh  = (unsigned short*)(ws + 6553600);   // 147456 u16
    unsigned short* wmodl  = (unsigned short*)(ws + 6627328);   // 147456 u16
    float* hesq   = ws + 6701056;                               // 4096
    float* m1v    = ws + 6705152;                               // 262144 (max N*SPL = 32768*8)
    float* m2v    = ws + 6967296;                               // 262144
    int*   m1i    = (int*)(ws + 7229440);                       // 262144
    int*   idx    = (int*)(ws + 7491584);                       // 32768
    int*   flag   = (int*)(ws + 7524352);                       // 32768
    int*   count  = (int*)(ws + 7557120);                       // 64
    unsigned long long* pmin = (unsigned long long*)(ws + 7557184); // 32768 u64
    float* vqp    = ws + 7622720;                               // 1536 (6*256)
    float* cmpP   = ws + 7624256;                               // 10240 (5*2048)

    hipMemsetAsync(d_out, 0, (size_t)out_size * sizeof(float), stream);
    hipMemsetAsync(count, 0, 6 * sizeof(int), stream);
    k_wmod<<<576, 256, 0, stream>>>(convw, fcw, fcb, wmodh, wmodl);
    k_embprep<<<16, 256, 0, stream>>>(embed, hesq, embhiN, embloN);

    const int pns[6]    = {1, 2, 4, 8, 16, 32};
    const int splits[6] = {64, 64, 64, 64, 16, 8};
    const int kidx[6]   = {0, 0, 1, 2, 3, 3};

    for (int si = 0; si < 6; ++si) {
        int pn = pns[si], pn2 = pn * pn;
        int N = 32 * pn2, SPL = splits[si], CPS = 4096 / SPL;

        // 1. downsample (f - f_hat) -> rest [N][64] f32 + bf16 hi/lo
        if (si <= 4) {
            k_down_plane<<<2048, 256, 0, stream>>>(f, out, restnc, resthi, restlo,
                                                   si >= 1 ? cmpP + (si - 1) * 2048 : nullptr, pn);
        } else {
            k_trans_nc<<<dim3(32, 16), 256, 0, stream>>>(f, out, restnc, resthi, restlo,
                                                         cmpP + 4 * 2048);
        }

        // 2. nearest codebook entry: MFMA approx top-2 -> combine (+pmin init) -> exact fallback
        k_vq_mfma<<<dim3((N + 255) / 256, SPL), 256, 0, stream>>>(resthi, restlo, embhiN, embloN, hesq,
                                                                  m1v, m1i, m2v, N, CPS);
        k_vq_combine<<<(N + 255) / 256, 256, 0, stream>>>(m1v, m1i, m2v, idx, flag, count + si, pmin, N, SPL);
        k_vq_exact<<<512, 256, 0, stream>>>(restnc, embed, hesq, flag, count + si, pmin);

        // 3. fused gather + upsample -> NHWC bf16 hi/lo
        k_up<<<(N_ELEM + 255) / 256, 256, 0, stream>>>(idx, pmin, embed, huph, hupl, pn);

        // 4. MFMA Phi conv + blend + f_hat update + vq loss partials
        k_conv_mfma<<<dim3(32, 8), 256, 0, stream>>>(huph, hupl,
                                                     wmodh + kidx[si] * 36864, wmodl + kidx[si] * 36864,
                                                     convb + kidx[si] * 64, f, out, vqp + si * 256);
    }

    k_final<<<1, 256, 0, stream>>>(vqp, cmpP, out);
}

// Round 10
// 609.932 us; speedup vs baseline: 1.0275x; 1.0275x over previous
//
#include <hip/hip_runtime.h>
#include <cfloat>

// Problem constants: B=32, C=64, H=W=32, V=4096, SN=6, RESI=0.5, BETA=0.25
#define N_ELEM 2097152   // 32*64*32*32
#define TAU 2.0e-2f      // approx-score decision margin (>> worst-case split-bf16 error ~5e-4)

typedef short s16x8 __attribute__((ext_vector_type(8)));
typedef float f32x4 __attribute__((ext_vector_type(4)));

__device__ __forceinline__ unsigned short f2bf(float v) {   // RNE float->bf16 bits
    unsigned u = __float_as_uint(v);
    u += 0x7FFFu + ((u >> 16) & 1u);
    return (unsigned short)(u >> 16);
}
__device__ __forceinline__ float bf2f(unsigned short h) {
    return __uint_as_float(((unsigned)h) << 16);
}

__device__ __forceinline__ float blockReduceSum(float v) {
    __shared__ float red[4];
    #pragma unroll
    for (int off = 32; off; off >>= 1) v += __shfl_down(v, off, 64);
    int wid = threadIdx.x >> 6, lane = threadIdx.x & 63;
    if (lane == 0) red[wid] = v;
    __syncthreads();
    float r = 0.f;
    if (threadIdx.x == 0) {
        int nw = ((int)blockDim.x + 63) >> 6;
        for (int w = 0; w < nw; ++w) r += red[w];
    }
    __syncthreads();
    return r;
}

// codebook prep: half squared norms (f32) + NEGATED bf16 hi/lo planes (C-init trick:
// acc = q + sum(-e * r) = q - dot => min-orientation top-2 logic unchanged)
__global__ void k_embprep(const float* __restrict__ e, float* __restrict__ hesq,
                          unsigned short* __restrict__ ehiN, unsigned short* __restrict__ eloN) {
    int v = blockIdx.x * 256 + threadIdx.x;
    if (v >= 4096) return;
    const float4* r = (const float4*)(e + (size_t)v * 64);
    float s = 0.f;
    #pragma unroll
    for (int i = 0; i < 16; ++i) {
        float4 a = r[i];
        s += a.x * a.x + a.y * a.y + a.z * a.z + a.w * a.w;
    }
    hesq[v] = 0.5f * s;
    for (int i = 0; i < 64; ++i) {
        float x = e[(size_t)v * 64 + i];
        unsigned short h = f2bf(x);
        ehiN[(size_t)v * 64 + i] = h ^ 0x8000u;
        eloN[(size_t)v * 64 + i] = f2bf(x - bf2f(h)) ^ 0x8000u;
    }
}

// modulated conv weights -> MFMA layout [k][tap][co][ci] bf16 hi/lo
__global__ void k_wmod(const float* __restrict__ w, const float* __restrict__ fcw,
                       const float* __restrict__ fcb,
                       unsigned short* __restrict__ wh, unsigned short* __restrict__ wl) {
    int i = blockIdx.x * 256 + threadIdx.x;
    if (i >= 4 * 64 * 64 * 9) return;
    int k = i / (64 * 64 * 9);
    int r = i % (64 * 64 * 9);
    int oi = r / 9;            // co*64 + ci
    int t = r % 9;
    int co = oi >> 6, ci = oi & 63;
    float cond = fcw[k * 4096 + oi] * 6.0f + fcb[k * 4096 + oi];
    float v = w[i] * (1.0f + cond);
    size_t o = ((size_t)(k * 9 + t) * 64 + co) * 64 + ci;
    unsigned short h = f2bf(v);
    wh[o] = h;
    wl[o] = f2bf(v - bf2f(h));
}

// ---- plane-parallel downsample: one block per (b,c), coalesced reads, LDS reduce ----
__global__ __launch_bounds__(256) void k_down_plane(
        const float* __restrict__ f, const float* __restrict__ fhat,
        float* __restrict__ restnc, unsigned short* __restrict__ dhi,
        unsigned short* __restrict__ dlo, float* __restrict__ cmpPrev, int pn) {
    __shared__ float hs[32][16];   // per-(row, x-pair) partial sums
    __shared__ float cr[32][16];   // per-(row, patch-col) sums
    __shared__ float pm[256];      // patch means (pn*pn <= 256 for pn<=16)
    int bc = blockIdx.x;           // b*64 + c
    int c = bc & 63, b = bc >> 6;
    int t = threadIdx.x;
    const float4* fp = (const float4*)(f + (size_t)bc * 1024);
    const float4* hp = (const float4*)(fhat + (size_t)bc * 1024);
    float4 a = fp[t], q = hp[t];
    int r = t >> 3, c4 = t & 7;
    hs[r][c4 * 2]     = (a.x - q.x) + (a.y - q.y);
    hs[r][c4 * 2 + 1] = (a.z - q.z) + (a.w - q.w);
    __syncthreads();
    int cpp = 16 / pn;             // x-pairs per patch column
    for (int i = t; i < 32 * pn; i += 256) {
        int rr = i / pn, px = i % pn;
        float s = 0.f;
        for (int j = 0; j < cpp; ++j) s += hs[rr][px * cpp + j];
        cr[rr][px] = s;
    }
    __syncthreads();
    int s_ = 32 / pn;
    float inv = 1.0f / (float)(s_ * s_);
    for (int p = t; p < pn * pn; p += 256) {
        int py = p / pn, px = p % pn;
        float s = 0.f;
        for (int j = 0; j < s_; ++j) s += cr[py * s_ + j][px];
        float m = s * inv;
        pm[p] = m;
        int n = (b * pn + py) * pn + px;
        size_t o = (size_t)n * 64 + c;
        unsigned short h = f2bf(m);
        restnc[o] = m;
        dhi[o] = h;
        dlo[o] = f2bf(m - bf2f(h));
    }
    if (pn >= 2) {
        __syncthreads();
        int pnp = pn >> 1;
        float m2 = 0.f;
        for (int p = t; p < pnp * pnp; p += 256) {
            int py = p / pnp, px = p % pnp;
            float mm = 0.25f * (pm[(2 * py) * pn + 2 * px] + pm[(2 * py) * pn + 2 * px + 1]
                              + pm[(2 * py + 1) * pn + 2 * px] + pm[(2 * py + 1) * pn + 2 * px + 1]);
            m2 += mm * mm;
        }
        m2 = blockReduceSum(m2);
        if (t == 0) cmpPrev[blockIdx.x] = m2;
    }
}

// NCHW plane-major [64][1024] per b -> [N][64] f32 + bf16 hi/lo of (f - fhat)  (si=5)
// + fused commit partial for si=4 -> cmp[bx*16 + by] (512 slots).
__global__ void k_trans_nc(const float* __restrict__ A, const float* __restrict__ Bt,
                           float* __restrict__ dst,
                           unsigned short* __restrict__ dhi, unsigned short* __restrict__ dlo,
                           float* __restrict__ cmp) {
    __shared__ float t[64][65];
    int b = blockIdx.x;
    int p0 = blockIdx.y * 64;
    int lane = threadIdx.x & 63, r4 = threadIdx.x >> 6;
    #pragma unroll
    for (int i = 0; i < 16; ++i) {
        int c = i * 4 + r4;
        size_t g = ((size_t)b * 64 + c) * 1024 + p0 + lane;
        t[c][lane] = A[g] - Bt[g];
    }
    __syncthreads();
    #pragma unroll
    for (int i = 0; i < 16; ++i) {
        int p = i * 4 + r4;
        size_t o = ((size_t)(b * 1024 + p0 + p)) * 64 + lane;
        float v = t[lane][p];
        unsigned short h = f2bf(v);
        dst[o] = v;
        dhi[o] = h;
        dlo[o] = f2bf(v - bf2f(h));
    }
    // commit si=4 partial: 64 c x 16 px 2x2-means
    float m2s = 0.f;
    for (int i = threadIdx.x; i < 1024; i += 256) {
        int c = i & 63, px = i >> 6;
        float m = 0.25f * (t[c][2 * px] + t[c][2 * px + 1] + t[c][32 + 2 * px] + t[c][33 + 2 * px]);
        m2s += m * m;
    }
    m2s = blockReduceSum(m2s);
    if (threadIdx.x == 0) cmp[blockIdx.x * 16 + blockIdx.y] = m2s;
}

// ---- MFMA VQ scan (round-7 form, measured 64.9us @si=5): 32 points/wave,
// negated-code C-init (acc = q - dot), med3 top-2 min ----
__global__ __launch_bounds__(256) void k_vq_mfma(
        const unsigned short* __restrict__ resthi, const unsigned short* __restrict__ restlo,
        const unsigned short* __restrict__ embhiN, const unsigned short* __restrict__ embloN,
        const float* __restrict__ hesq,
        float* __restrict__ m1v_, int* __restrict__ m1i_, float* __restrict__ m2v_,
        int N, int CPS) {
    __shared__ __align__(16) unsigned short lah[64 * 64];
    __shared__ __align__(16) unsigned short lal[64 * 64];
    __shared__ __align__(16) float lq[64];
    int tid = threadIdx.x;
    int lane = tid & 63, wv = tid >> 6;
    int split = blockIdx.y;
    int p0 = blockIdx.x * 128 + wv * 32;
    int cr = lane & 15, oct = lane >> 4;
    int ko8 = oct * 8;
    int ptA = p0 + cr, ptB = p0 + 16 + cr;
    int pA = min(ptA, N - 1), pB = min(ptB, N - 1);

    const unsigned short* ra = resthi + (size_t)pA * 64;
    const unsigned short* la = restlo + (size_t)pA * 64;
    const unsigned short* rb = resthi + (size_t)pB * 64;
    const unsigned short* lb = restlo + (size_t)pB * 64;
    s16x8 bhA0 = *(const s16x8*)(ra + ko8);
    s16x8 bhA1 = *(const s16x8*)(ra + 32 + ko8);
    s16x8 blA0 = *(const s16x8*)(la + ko8);
    s16x8 blA1 = *(const s16x8*)(la + 32 + ko8);
    s16x8 bhB0 = *(const s16x8*)(rb + ko8);
    s16x8 bhB1 = *(const s16x8*)(rb + 32 + ko8);
    s16x8 blB0 = *(const s16x8*)(lb + ko8);
    s16x8 blB1 = *(const s16x8*)(lb + 32 + ko8);

    float m1vA = FLT_MAX, m2vA = FLT_MAX; int m1iA = 0;
    float m1vB = FLT_MAX, m2vB = FLT_MAX; int m1iB = 0;
    int sw = (cr & 7) << 4;    // sub-invariant: (cl&7) == (cr&7)

    int cbeg = split * CPS;
    for (int oc = 0; oc < CPS; oc += 64) {
        int cb = cbeg + oc;
        __syncthreads();
        for (int t = tid; t < 512; t += 256) {
            int cc = t >> 3, part = t & 7;
            int bo = (cc * 128 + part * 16) ^ ((cc & 7) << 4);
            *(uint4*)((char*)lah + bo) = *(const uint4*)(embhiN + (size_t)(cb + cc) * 64 + part * 8);
            *(uint4*)((char*)lal + bo) = *(const uint4*)(embloN + (size_t)(cb + cc) * 64 + part * 8);
        }
        if (tid < 64) lq[tid] = hesq[cb + tid];
        __syncthreads();
        #pragma unroll
        for (int sub = 0; sub < 4; ++sub) {
            int rowb = (sub * 16 + cr) * 128;
            s16x8 ah0 = *(const s16x8*)((const char*)lah + ((rowb + ko8 * 2) ^ sw));
            s16x8 ah1 = *(const s16x8*)((const char*)lah + ((rowb + 64 + ko8 * 2) ^ sw));
            s16x8 al0 = *(const s16x8*)((const char*)lal + ((rowb + ko8 * 2) ^ sw));
            s16x8 al1 = *(const s16x8*)((const char*)lal + ((rowb + 64 + ko8 * 2) ^ sw));
            f32x4 q = *(const f32x4*)(lq + sub * 16 + oct * 4);
            int crow = cb + sub * 16 + oct * 4;
            f32x4 acc = q;
            acc = __builtin_amdgcn_mfma_f32_16x16x32_bf16(ah0, bhA0, acc, 0, 0, 0);
            acc = __builtin_amdgcn_mfma_f32_16x16x32_bf16(ah1, bhA1, acc, 0, 0, 0);
            acc = __builtin_amdgcn_mfma_f32_16x16x32_bf16(ah0, blA0, acc, 0, 0, 0);
            acc = __builtin_amdgcn_mfma_f32_16x16x32_bf16(ah1, blA1, acc, 0, 0, 0);
            acc = __builtin_amdgcn_mfma_f32_16x16x32_bf16(al0, bhA0, acc, 0, 0, 0);
            acc = __builtin_amdgcn_mfma_f32_16x16x32_bf16(al1, bhA1, acc, 0, 0, 0);
            #pragma unroll
            for (int r = 0; r < 4; ++r) {
                float s = acc[r];
                bool lt = s < m1vA;
                m2vA = fminf(fmaxf(s, m1vA), m2vA);
                m1iA = lt ? (crow + r) : m1iA;
                m1vA = fminf(s, m1vA);
            }
            f32x4 accB = q;
            accB = __builtin_amdgcn_mfma_f32_16x16x32_bf16(ah0, bhB0, accB, 0, 0, 0);
            accB = __builtin_amdgcn_mfma_f32_16x16x32_bf16(ah1, bhB1, accB, 0, 0, 0);
            accB = __builtin_amdgcn_mfma_f32_16x16x32_bf16(ah0, blB0, accB, 0, 0, 0);
            accB = __builtin_amdgcn_mfma_f32_16x16x32_bf16(ah1, blB1, accB, 0, 0, 0);
            accB = __builtin_amdgcn_mfma_f32_16x16x32_bf16(al0, bhB0, accB, 0, 0, 0);
            accB = __builtin_amdgcn_mfma_f32_16x16x32_bf16(al1, bhB1, accB, 0, 0, 0);
            #pragma unroll
            for (int r = 0; r < 4; ++r) {
                float s = accB[r];
                bool lt = s < m1vB;
                m2vB = fminf(fmaxf(s, m1vB), m2vB);
                m1iB = lt ? (crow + r) : m1iB;
                m1vB = fminf(s, m1vB);
            }
        }
    }
    #pragma unroll
    for (int off = 16; off <= 32; off <<= 1) {
        float o1 = __shfl_xor(m1vA, off, 64); int oi = __shfl_xor(m1iA, off, 64);
        float o2 = __shfl_xor(m2vA, off, 64);
        bool lt = o1 < m1vA;
        m2vA = fminf(fmaxf(o1, m1vA), fminf(m2vA, o2));
        m1vA = fminf(o1, m1vA);
        m1iA = lt ? oi : m1iA;
        o1 = __shfl_xor(m1vB, off, 64); oi = __shfl_xor(m1iB, off, 64);
        o2 = __shfl_xor(m2vB, off, 64);
        lt = o1 < m1vB;
        m2vB = fminf(fmaxf(o1, m1vB), fminf(m2vB, o2));
        m1vB = fminf(o1, m1vB);
        m1iB = lt ? oi : m1iB;
    }
    if (oct == 0) {
        if (ptA < N) { size_t o = (size_t)split * N + ptA; m1v_[o] = m1vA; m1i_[o] = m1iA; m2v_[o] = m2vA; }
        if (ptB < N) { size_t o = (size_t)split * N + ptB; m1v_[o] = m1vB; m1i_[o] = m1iB; m2v_[o] = m2vB; }
    }
}

// merge split partials; init pmin; decide or flag for exact fallback
__global__ void k_vq_combine(const float* __restrict__ m1v_, const int* __restrict__ m1i_,
                             const float* __restrict__ m2v_,
                             int* __restrict__ idx, int* __restrict__ flag, int* __restrict__ count,
                             unsigned long long* __restrict__ pmin, int N, int SPLITS) {
    int n = blockIdx.x * 256 + threadIdx.x;
    if (n >= N) return;
    float a1v = m1v_[n], a2v = m2v_[n];
    int a1i = m1i_[n];
    for (int s = 1; s < SPLITS; ++s) {
        size_t o = (size_t)s * N + n;
        float b1v = m1v_[o], b2v = m2v_[o];
        int b1i = m1i_[o];
        bool lt = b1v < a1v;
        a2v = fminf(fmaxf(b1v, a1v), fminf(a2v, b2v));
        a1v = fminf(b1v, a1v);
        a1i = lt ? b1i : a1i;
    }
    idx[n] = a1i;
    pmin[n] = 0xFFFFFFFFFFFFFFFFull;
    if (a2v - a1v < TAU) {
        int p = atomicAdd(count, 1);
        flag[p] = n;
    }
}

// exact f32 rescan for flagged points (wave-level atomicMin)
__global__ __launch_bounds__(256) void k_vq_exact(
        const float* __restrict__ restnc, const float* __restrict__ embed,
        const float* __restrict__ hesq, const int* __restrict__ flag,
        const int* __restrict__ count, unsigned long long* __restrict__ pmin) {
    __shared__ float rs[32 * 64];
    int tid = threadIdx.x;
    int lane = tid & 63;
    int cnt = *count;
    int nb = (cnt + 31) >> 5;
    int ntask = nb * 16;
    for (int task = blockIdx.x; task < ntask; task += gridDim.x) {
        int batch = task >> 4, spl = task & 15;
        int lbase = batch << 5;
        int npts = min(32, cnt - lbase);
        __syncthreads();
        for (int i = tid; i < npts * 64; i += 256) {
            int li = i >> 6;
            rs[i] = restnc[(size_t)flag[lbase + li] * 64 + (i & 63)];
        }
        __syncthreads();
        int code = spl * 256 + tid;
        const float4* e4 = (const float4*)(embed + (size_t)code * 64);
        float4 e[16];
        #pragma unroll
        for (int i = 0; i < 16; ++i) e[i] = e4[i];
        float hq = hesq[code];
        for (int p = 0; p < npts; ++p) {
            const float4* r4 = (const float4*)(rs + p * 64);
            float d0 = 0.f, d1 = 0.f, d2 = 0.f, d3 = 0.f;
            #pragma unroll
            for (int i = 0; i < 16; i += 4) {
                float4 e0 = e[i], e1 = e[i + 1], e2 = e[i + 2], e3 = e[i + 3];
                d0 += e0.x * r4[i].x     + e0.y * r4[i].y     + e0.z * r4[i].z     + e0.w * r4[i].w;
                d1 += e1.x * r4[i + 1].x + e1.y * r4[i + 1].y + e1.z * r4[i + 1].z + e1.w * r4[i + 1].w;
                d2 += e2.x * r4[i + 2].x + e2.y * r4[i + 2].y + e2.z * r4[i + 2].z + e2.w * r4[i + 2].w;
                d3 += e3.x * r4[i + 3].x + e3.y * r4[i + 3].y + e3.z * r4[i + 3].z + e3.w * r4[i + 3].w;
            }
            float s = hq - ((d0 + d1) + (d2 + d3));
            unsigned u = __float_as_uint(s);
            u = (u & 0x80000000u) ? ~u : (u | 0x80000000u);
            unsigned long long pk = (((unsigned long long)u) << 32) | (unsigned)code;
            #pragma unroll
            for (int off = 32; off; off >>= 1) {
                unsigned long long o = __shfl_down(pk, off, 64);
                if (o < pk) pk = o;
            }
            if (lane == 0) atomicMin(pmin + flag[lbase + p], pk);
        }
    }
}

// ---- MFMA 3x3 conv with FUSED gather+bilinear staging (k_up eliminated) ----
// grid (32 b, 16 rg): 2 output rows per block; halo 4 rows x 34 cols.
// Phase A: per-halo-pixel code-index + weight resolve. Phase B: gather from embed,
// lerp, bf16 hi/lo split -> XOR-swizzled LDS. Then 2 co-tiles x 2 px-tiles per wave,
// 3-term split MFMA; blend operand h = hi+lo read back from LDS.
__global__ __launch_bounds__(256) void k_conv_mfma(
        const int* __restrict__ idx, const unsigned long long* __restrict__ pmin,
        const float* __restrict__ embed,
        const unsigned short* __restrict__ wh, const unsigned short* __restrict__ wl,
        const float* __restrict__ bias, const float* __restrict__ f_in,
        float* __restrict__ f_hat, float* __restrict__ vq_part, int pn) {
    __shared__ __align__(16) unsigned short Xh[4 * 34 * 64];
    __shared__ __align__(16) unsigned short Xl[4 * 34 * 64];
    __shared__ int pid[136][4];
    __shared__ float pwt[136][2];
    int b = blockIdx.x, rg = blockIdx.y;
    int y0 = rg * 2;
    int tid = threadIdx.x;
    int lane = tid & 63, wv = tid >> 6;
    int coh = (wv & 1) * 32;       // co half
    int ph  = (wv >> 1) * 2;       // px-tile base (2 tiles = 1 row)
    int cr = lane & 15, oct = lane >> 4;

    // Phase A: resolve bilinear source codes + weights per halo pixel
    if (tid < 136) {
        int lr = tid / 34, lc = tid % 34;
        int gy = y0 + lr - 1, gx = lc - 1;
        if (gy >= 0 && gy < 32 && gx >= 0 && gx < 32) {
            if (pn == 32) {
                int n = (b * 32 + gy) * 32 + gx;
                unsigned long long pv = pmin[n];
                int id = (pv != 0xFFFFFFFFFFFFFFFFull) ? (int)(pv & 0xFFFFFFFFull) : idx[n];
                pid[tid][0] = id; pid[tid][1] = id; pid[tid][2] = id; pid[tid][3] = id;
                pwt[tid][0] = 0.f; pwt[tid][1] = 0.f;
            } else {
                float scale = (float)pn * (1.0f / 32.0f);
                float sy = (gy + 0.5f) * scale - 0.5f;
                float sx = (gx + 0.5f) * scale - 0.5f;
                float fy0 = floorf(sy), fx0 = floorf(sx);
                float wy = sy - fy0, wx = sx - fx0;
                int yy0 = max(0, min(pn - 1, (int)fy0));
                int yy1 = max(0, min(pn - 1, (int)fy0 + 1));
                int xx0 = max(0, min(pn - 1, (int)fx0));
                int xx1 = max(0, min(pn - 1, (int)fx0 + 1));
                int nb_ = b * pn * pn;
                int n00 = nb_ + yy0 * pn + xx0, n01 = nb_ + yy0 * pn + xx1;
                int n10 = nb_ + yy1 * pn + xx0, n11 = nb_ + yy1 * pn + xx1;
                unsigned long long p00 = pmin[n00], p01 = pmin[n01];
                unsigned long long p10 = pmin[n10], p11 = pmin[n11];
                pid[tid][0] = (p00 != 0xFFFFFFFFFFFFFFFFull) ? (int)(p00 & 0xFFFFFFFFull) : idx[n00];
                pid[tid][1] = (p01 != 0xFFFFFFFFFFFFFFFFull) ? (int)(p01 & 0xFFFFFFFFull) : idx[n01];
                pid[tid][2] = (p10 != 0xFFFFFFFFFFFFFFFFull) ? (int)(p10 & 0xFFFFFFFFull) : idx[n10];
                pid[tid][3] = (p11 != 0xFFFFFFFFFFFFFFFFull) ? (int)(p11 & 0xFFFFFFFFull) : idx[n11];
                pwt[tid][0] = wy; pwt[tid][1] = wx;
            }
        } else {
            pid[tid][0] = -1;
        }
    }
    __syncthreads();

    // Phase B: gather + lerp + split -> LDS (136 pixels x 8 chunks)
    for (int q = tid; q < 136 * 8; q += 256) {
        int pl = q >> 3, o8 = q & 7;
        int lc = pl % 34;
        int bo = (pl * 128 + o8 * 16) ^ ((lc & 7) << 4);
        uint4 vh = {0, 0, 0, 0}, vl = {0, 0, 0, 0};
        int i00 = pid[pl][0];
        if (i00 >= 0) {
            int i01 = pid[pl][1], i10 = pid[pl][2], i11 = pid[pl][3];
            float wy = pwt[pl][0], wx = pwt[pl][1];
            const float4* e00 = (const float4*)(embed + (size_t)i00 * 64 + o8 * 8);
            const float4* e01 = (const float4*)(embed + (size_t)i01 * 64 + o8 * 8);
            const float4* e10 = (const float4*)(embed + (size_t)i10 * 64 + o8 * 8);
            const float4* e11 = (const float4*)(embed + (size_t)i11 * 64 + o8 * 8);
            union { unsigned short u[8]; uint4 v; } oh, ol;
            #pragma unroll
            for (int half = 0; half < 2; ++half) {
                float4 a00 = e00[half], a01 = e01[half], a10 = e10[half], a11 = e11[half];
                float vv[4];
                vv[0] = (a00.x + wx * (a01.x - a00.x)) + wy * ((a10.x + wx * (a11.x - a10.x)) - (a00.x + wx * (a01.x - a00.x)));
                vv[1] = (a00.y + wx * (a01.y - a00.y)) + wy * ((a10.y + wx * (a11.y - a10.y)) - (a00.y + wx * (a01.y - a00.y)));
                vv[2] = (a00.z + wx * (a01.z - a00.z)) + wy * ((a10.z + wx * (a11.z - a10.z)) - (a00.z + wx * (a01.z - a00.z)));
                vv[3] = (a00.w + wx * (a01.w - a00.w)) + wy * ((a10.w + wx * (a11.w - a10.w)) - (a00.w + wx * (a01.w - a00.w)));
                #pragma unroll
                for (int j = 0; j < 4; ++j) {
                    unsigned short h = f2bf(vv[j]);
                    oh.u[half * 4 + j] = h;
                    ol.u[half * 4 + j] = f2bf(vv[j] - bf2f(h));
                }
            }
            vh = oh.v; vl = ol.v;
        }
        *(uint4*)((char*)Xh + bo) = vh;
        *(uint4*)((char*)Xl + bo) = vl;
    }
    __syncthreads();

    f32x4 acc[2][2];
    #pragma unroll
    for (int ct = 0; ct < 2; ++ct)
        #pragma unroll
        for (int pp = 0; pp < 2; ++pp) acc[ct][pp] = (f32x4){0.f, 0.f, 0.f, 0.f};

    for (int t = 0; t < 9; ++t) {
        int dy = t / 3, dx = t % 3;
        #pragma unroll
        for (int cc = 0; cc < 2; ++cc) {
            size_t wo0 = ((size_t)t * 64 + coh + cr) * 64 + cc * 32 + oct * 8;
            size_t wo1 = ((size_t)t * 64 + coh + 16 + cr) * 64 + cc * 32 + oct * 8;
            s16x8 Ah0 = *(const s16x8*)(wh + wo0);
            s16x8 Al0 = *(const s16x8*)(wl + wo0);
            s16x8 Ah1 = *(const s16x8*)(wh + wo1);
            s16x8 Al1 = *(const s16x8*)(wl + wo1);
            #pragma unroll
            for (int pp = 0; pp < 2; ++pp) {
                int px = (ph + pp) * 16 + cr;
                int lr = (px >> 5) + dy;
                int lc = (px & 31) + dx;
                int bo = ((lr * 34 + lc) * 128 + cc * 64 + oct * 16) ^ ((lc & 7) << 4);
                s16x8 Bh = *(const s16x8*)((const char*)Xh + bo);
                s16x8 Bl = *(const s16x8*)((const char*)Xl + bo);
                acc[0][pp] = __builtin_amdgcn_mfma_f32_16x16x32_bf16(Ah0, Bh, acc[0][pp], 0, 0, 0);
                acc[0][pp] = __builtin_amdgcn_mfma_f32_16x16x32_bf16(Ah0, Bl, acc[0][pp], 0, 0, 0);
                acc[0][pp] = __builtin_amdgcn_mfma_f32_16x16x32_bf16(Al0, Bh, acc[0][pp], 0, 0, 0);
                acc[1][pp] = __builtin_amdgcn_mfma_f32_16x16x32_bf16(Ah1, Bh, acc[1][pp], 0, 0, 0);
                acc[1][pp] = __builtin_amdgcn_mfma_f32_16x16x32_bf16(Ah1, Bl, acc[1][pp], 0, 0, 0);
                acc[1][pp] = __builtin_amdgcn_mfma_f32_16x16x32_bf16(Al1, Bh, acc[1][pp], 0, 0, 0);
            }
        }
    }

    // epilogue: D row (co-in-tile) = oct*4 + r, D col (px-in-tile) = cr
    float local = 0.f;
    #pragma unroll
    for (int ct = 0; ct < 2; ++ct) {
        int cbase = coh + ct * 16 + oct * 4;
        #pragma unroll
        for (int pp = 0; pp < 2; ++pp) {
            int px = (ph + pp) * 16 + cr;
            int y = y0 + (px >> 5), x = px & 31;
            int lr = (px >> 5) + 1, lc = (px & 31) + 1;
            int bo = ((lr * 34 + lc) * 128 + cbase * 2) ^ ((lc & 7) << 4);
            ushort4 hvh = *(const ushort4*)((const char*)Xh + bo);
            ushort4 hvl = *(const ushort4*)((const char*)Xl + bo);
            #pragma unroll
            for (int r = 0; r < 4; ++r) {
                int co = cbase + r;
                unsigned short uh = (r == 0) ? hvh.x : (r == 1) ? hvh.y : (r == 2) ? hvh.z : hvh.w;
                unsigned short ul = (r == 0) ? hvl.x : (r == 1) ? hvl.y : (r == 2) ? hvl.z : hvl.w;
                float hv = bf2f(uh) + bf2f(ul);
                float hconv = acc[ct][pp][r] + bias[co];
                float hout = 0.5f * hv + 0.5f * hconv;
                size_t o = (((size_t)(b * 64 + co)) * 32 + y) * 32 + x;
                float fh = f_hat[o] + hout;
                f_hat[o] = fh;
                float d = fh - f_in[o];
                local += d * d;
            }
        }
    }
    local = blockReduceSum(local);
    if (tid == 0) vq_part[b * 16 + rg] = local;
}

// final: vq losses from vqp (6x512), commit from cmpP (per-scale slot counts) + vq5 identity
__global__ void k_final(const float* __restrict__ vqp, const float* __restrict__ cmpP,
                        float* __restrict__ out) {
    const int pn2s[5] = {1, 4, 16, 64, 256};
    const int slots[5] = {2048, 2048, 2048, 2048, 512};
    __shared__ float commit_s;
    if (threadIdx.x == 0) commit_s = 0.f;
    __syncthreads();
    for (int si = 0; si < 6; ++si) {
        float l = vqp[si * 512 + threadIdx.x] + vqp[si * 512 + 256 + threadIdx.x];
        l = blockReduceSum(l);
        if (threadIdx.x == 0) {
            float vl = l / (float)N_ELEM;
            out[N_ELEM + si] = vl;
            if (si == 5) commit_s += vl * 0.25f;   // commit(si=5) == vq loss 5
        }
        if (si < 5) {
            float csum = 0.f;
            for (int i = threadIdx.x; i < slots[si]; i += 256) csum += cmpP[si * 2048 + i];
            csum = blockReduceSum(csum);
            if (threadIdx.x == 0) commit_s += csum / (float)(2048 * pn2s[si]) * 0.25f;
        }
    }
    __syncthreads();
    if (threadIdx.x == 0) out[N_ELEM + 6] = commit_s / 6.0f;
}

extern "C" void kernel_launch(void* const* d_in, const int* in_sizes, int n_in,
                              void* d_out, int out_size, void* d_ws, size_t ws_size,
                              hipStream_t stream) {
    const float* f     = (const float*)d_in[0];
    const float* embed = (const float*)d_in[1];
    const float* convw = (const float*)d_in[2];
    const float* convb = (const float*)d_in[3];
    const float* fcw   = (const float*)d_in[4];
    const float* fcb   = (const float*)d_in[5];
    float* out = (float*)d_out;        // f_hat lives in out[0..N_ELEM)
    float* ws  = (float*)d_ws;

    float* restnc = ws + 2097152;                               // 2097152
    unsigned short* resthi = (unsigned short*)(ws + 4194304);   // 2M u16
    unsigned short* restlo = (unsigned short*)(ws + 5242880);   // 2M u16
    unsigned short* embhiN = (unsigned short*)(ws + 6291456);   // 262144 u16
    unsigned short* embloN = (unsigned short*)(ws + 6422528);   // 262144 u16
    unsigned short* wmodh  = (unsigned short*)(ws + 6553600);   // 147456 u16
    unsigned short* wmodl  = (unsigned short*)(ws + 6627328);   // 147456 u16
    float* hesq   = ws + 6701056;                               // 4096
    float* m1v    = ws + 6705152;                               // 262144 (max N*SPL)
    float* m2v    = ws + 6967296;                               // 262144
    int*   m1i    = (int*)(ws + 7229440);                       // 262144
    int*   idx    = (int*)(ws + 7491584);                       // 32768
    int*   flag   = (int*)(ws + 7524352);                       // 32768
    int*   count  = (int*)(ws + 7557120);                       // 64
    unsigned long long* pmin = (unsigned long long*)(ws + 7557184); // 32768 u64
    float* vqp    = ws + 7622720;                               // 3072 (6*512)
    float* cmpP   = ws + 7625792;                               // 10240 (5*2048)

    hipMemsetAsync(d_out, 0, (size_t)out_size * sizeof(float), stream);
    hipMemsetAsync(count, 0, 6 * sizeof(int), stream);
    k_wmod<<<576, 256, 0, stream>>>(convw, fcw, fcb, wmodh, wmodl);
    k_embprep<<<16, 256, 0, stream>>>(embed, hesq, embhiN, embloN);

    const int pns[6]    = {1, 2, 4, 8, 16, 32};
    const int splits[6] = {64, 64, 64, 64, 16, 8};
    const int kidx[6]   = {0, 0, 1, 2, 3, 3};

    for (int si = 0; si < 6; ++si) {
        int pn = pns[si], pn2 = pn * pn;
        int N = 32 * pn2, SPL = splits[si], CPS = 4096 / SPL;

        // 1. downsample (f - f_hat) -> rest [N][64] f32 + bf16 hi/lo
        if (si <= 4) {
            k_down_plane<<<2048, 256, 0, stream>>>(f, out, restnc, resthi, restlo,
                                                   si >= 1 ? cmpP + (si - 1) * 2048 : nullptr, pn);
        } else {
            k_trans_nc<<<dim3(32, 16), 256, 0, stream>>>(f, out, restnc, resthi, restlo,
                                                         cmpP + 4 * 2048);
        }

        // 2. nearest codebook entry: MFMA approx top-2 -> combine (+pmin init) -> exact fallback
        k_vq_mfma<<<dim3((N + 127) / 128, SPL), 256, 0, stream>>>(resthi, restlo, embhiN, embloN, hesq,
                                                                  m1v, m1i, m2v, N, CPS);
        k_vq_combine<<<(N + 255) / 256, 256, 0, stream>>>(m1v, m1i, m2v, idx, flag, count + si, pmin, N, SPL);
        k_vq_exact<<<512, 256, 0, stream>>>(restnc, embed, hesq, flag, count + si, pmin);

        // 3+4. fused gather/upsample + MFMA Phi conv + blend + f_hat update + vq partials
        k_conv_mfma<<<dim3(32, 16), 256, 0, stream>>>(idx, pmin, embed,
                                                      wmodh + kidx[si] * 36864, wmodl + kidx[si] * 36864,
                                                      convb + kidx[si] * 64, f, out, vqp + si * 512, pn);
    }

    k_final<<<1, 256, 0, stream>>>(vqp, cmpP, out);
}

// Round 12
// 587.129 us; speedup vs baseline: 1.0674x; 1.0388x over previous
//
#include <hip/hip_runtime.h>
#include <cfloat>

// Problem constants: B=32, C=64, H=W=32, V=4096, SN=6, RESI=0.5, BETA=0.25
#define N_ELEM 2097152   // 32*64*32*32
#define TAU 2.0e-2f      // approx-score decision margin (>> worst-case split-bf16 error ~5e-4)

typedef short s16x8 __attribute__((ext_vector_type(8)));
typedef float f32x4 __attribute__((ext_vector_type(4)));

__device__ __forceinline__ unsigned short f2bf(float v) {   // RNE float->bf16 bits
    unsigned u = __float_as_uint(v);
    u += 0x7FFFu + ((u >> 16) & 1u);
    return (unsigned short)(u >> 16);
}
__device__ __forceinline__ float bf2f(unsigned short h) {
    return __uint_as_float(((unsigned)h) << 16);
}

__device__ __forceinline__ float blockReduceSum(float v) {
    __shared__ float red[8];
    #pragma unroll
    for (int off = 32; off; off >>= 1) v += __shfl_down(v, off, 64);
    int wid = threadIdx.x >> 6, lane = threadIdx.x & 63;
    if (lane == 0) red[wid] = v;
    __syncthreads();
    float r = 0.f;
    if (threadIdx.x == 0) {
        int nw = ((int)blockDim.x + 63) >> 6;
        for (int w = 0; w < nw; ++w) r += red[w];
    }
    __syncthreads();
    return r;
}

// codebook prep: half squared norms (f32) + NEGATED bf16 hi/lo planes (C-init trick:
// acc = q + sum(-e * r) = q - dot => min-orientation top-2 logic unchanged).
// Also zeroes the per-launch count[6] accumulator (blockIdx 0).
__global__ void k_embprep(const float* __restrict__ e, float* __restrict__ hesq,
                          unsigned short* __restrict__ ehiN, unsigned short* __restrict__ eloN,
                          int* __restrict__ count) {
    if (blockIdx.x == 0 && threadIdx.x < 6) count[threadIdx.x] = 0;
    int v = blockIdx.x * 256 + threadIdx.x;
    if (v >= 4096) return;
    const float4* r = (const float4*)(e + (size_t)v * 64);
    float s = 0.f;
    #pragma unroll
    for (int i = 0; i < 16; ++i) {
        float4 a = r[i];
        s += a.x * a.x + a.y * a.y + a.z * a.z + a.w * a.w;
    }
    hesq[v] = 0.5f * s;
    for (int i = 0; i < 64; ++i) {
        float x = e[(size_t)v * 64 + i];
        unsigned short h = f2bf(x);
        ehiN[(size_t)v * 64 + i] = h ^ 0x8000u;
        eloN[(size_t)v * 64 + i] = f2bf(x - bf2f(h)) ^ 0x8000u;
    }
}

// modulated conv weights -> MFMA layout [k][tap][co][ci] bf16 hi/lo
__global__ void k_wmod(const float* __restrict__ w, const float* __restrict__ fcw,
                       const float* __restrict__ fcb,
                       unsigned short* __restrict__ wh, unsigned short* __restrict__ wl) {
    int i = blockIdx.x * 256 + threadIdx.x;
    if (i >= 4 * 64 * 64 * 9) return;
    int k = i / (64 * 64 * 9);
    int r = i % (64 * 64 * 9);
    int oi = r / 9;            // co*64 + ci
    int t = r % 9;
    int co = oi >> 6, ci = oi & 63;
    float cond = fcw[k * 4096 + oi] * 6.0f + fcb[k * 4096 + oi];
    float v = w[i] * (1.0f + cond);
    size_t o = ((size_t)(k * 9 + t) * 64 + co) * 64 + ci;
    unsigned short h = f2bf(v);
    wh[o] = h;
    wl[o] = f2bf(v - bf2f(h));
}

// ---- plane-parallel downsample: one block per (b,c), coalesced reads, LDS reduce ----
__global__ __launch_bounds__(256) void k_down_plane(
        const float* __restrict__ f, const float* __restrict__ fhat,
        float* __restrict__ restnc, unsigned short* __restrict__ dhi,
        unsigned short* __restrict__ dlo, float* __restrict__ cmpPrev, int pn) {
    __shared__ float hs[32][16];   // per-(row, x-pair) partial sums
    __shared__ float cr[32][16];   // per-(row, patch-col) sums
    __shared__ float pm[256];      // patch means (pn*pn <= 256 for pn<=16)
    int bc = blockIdx.x;           // b*64 + c
    int c = bc & 63, b = bc >> 6;
    int t = threadIdx.x;
    const float4* fp = (const float4*)(f + (size_t)bc * 1024);
    const float4* hp = (const float4*)(fhat + (size_t)bc * 1024);
    float4 a = fp[t], q = hp[t];
    int r = t >> 3, c4 = t & 7;
    hs[r][c4 * 2]     = (a.x - q.x) + (a.y - q.y);
    hs[r][c4 * 2 + 1] = (a.z - q.z) + (a.w - q.w);
    __syncthreads();
    int cpp = 16 / pn;             // x-pairs per patch column
    for (int i = t; i < 32 * pn; i += 256) {
        int rr = i / pn, px = i % pn;
        float s = 0.f;
        for (int j = 0; j < cpp; ++j) s += hs[rr][px * cpp + j];
        cr[rr][px] = s;
    }
    __syncthreads();
    int s_ = 32 / pn;
    float inv = 1.0f / (float)(s_ * s_);
    for (int p = t; p < pn * pn; p += 256) {
        int py = p / pn, px = p % pn;
        float s = 0.f;
        for (int j = 0; j < s_; ++j) s += cr[py * s_ + j][px];
        float m = s * inv;
        pm[p] = m;
        int n = (b * pn + py) * pn + px;
        size_t o = (size_t)n * 64 + c;
        unsigned short h = f2bf(m);
        restnc[o] = m;
        dhi[o] = h;
        dlo[o] = f2bf(m - bf2f(h));
    }
    if (pn >= 2) {
        __syncthreads();
        int pnp = pn >> 1;
        float m2 = 0.f;
        for (int p = t; p < pnp * pnp; p += 256) {
            int py = p / pnp, px = p % pnp;
            float mm = 0.25f * (pm[(2 * py) * pn + 2 * px] + pm[(2 * py) * pn + 2 * px + 1]
                              + pm[(2 * py + 1) * pn + 2 * px] + pm[(2 * py + 1) * pn + 2 * px + 1]);
            m2 += mm * mm;
        }
        m2 = blockReduceSum(m2);
        if (t == 0) cmpPrev[blockIdx.x] = m2;
    }
}

// NCHW plane-major [64][1024] per b -> [N][64] f32 + bf16 hi/lo of (f - fhat)  (si=5)
// + fused commit partial for si=4 -> cmp[bx*16 + by] (512 slots).
__global__ void k_trans_nc(const float* __restrict__ A, const float* __restrict__ Bt,
                           float* __restrict__ dst,
                           unsigned short* __restrict__ dhi, unsigned short* __restrict__ dlo,
                           float* __restrict__ cmp) {
    __shared__ float t[64][65];
    int b = blockIdx.x;
    int p0 = blockIdx.y * 64;
    int lane = threadIdx.x & 63, r4 = threadIdx.x >> 6;
    #pragma unroll
    for (int i = 0; i < 16; ++i) {
        int c = i * 4 + r4;
        size_t g = ((size_t)b * 64 + c) * 1024 + p0 + lane;
        t[c][lane] = A[g] - Bt[g];
    }
    __syncthreads();
    #pragma unroll
    for (int i = 0; i < 16; ++i) {
        int p = i * 4 + r4;
        size_t o = ((size_t)(b * 1024 + p0 + p)) * 64 + lane;
        float v = t[lane][p];
        unsigned short h = f2bf(v);
        dst[o] = v;
        dhi[o] = h;
        dlo[o] = f2bf(v - bf2f(h));
    }
    // commit si=4 partial: 64 c x 16 px 2x2-means
    float m2s = 0.f;
    for (int i = threadIdx.x; i < 1024; i += 256) {
        int c = i & 63, px = i >> 6;
        float m = 0.25f * (t[c][2 * px] + t[c][2 * px + 1] + t[c][32 + 2 * px] + t[c][33 + 2 * px]);
        m2s += m * m;
    }
    m2s = blockReduceSum(m2s);
    if (threadIdx.x == 0) cmp[blockIdx.x * 16 + blockIdx.y] = m2s;
}

// ---- MFMA VQ scan (proven form, 64.5us @si=5): 32 points/wave,
// negated-code C-init (acc = q - dot), med3 top-2 min ----
__global__ __launch_bounds__(256) void k_vq_mfma(
        const unsigned short* __restrict__ resthi, const unsigned short* __restrict__ restlo,
        const unsigned short* __restrict__ embhiN, const unsigned short* __restrict__ embloN,
        const float* __restrict__ hesq,
        float* __restrict__ m1v_, int* __restrict__ m1i_, float* __restrict__ m2v_,
        int N, int CPS) {
    __shared__ __align__(16) unsigned short lah[64 * 64];
    __shared__ __align__(16) unsigned short lal[64 * 64];
    __shared__ __align__(16) float lq[64];
    int tid = threadIdx.x;
    int lane = tid & 63, wv = tid >> 6;
    int split = blockIdx.y;
    int p0 = blockIdx.x * 128 + wv * 32;
    int cr = lane & 15, oct = lane >> 4;
    int ko8 = oct * 8;
    int ptA = p0 + cr, ptB = p0 + 16 + cr;
    int pA = min(ptA, N - 1), pB = min(ptB, N - 1);

    const unsigned short* ra = resthi + (size_t)pA * 64;
    const unsigned short* la = restlo + (size_t)pA * 64;
    const unsigned short* rb = resthi + (size_t)pB * 64;
    const unsigned short* lb = restlo + (size_t)pB * 64;
    s16x8 bhA0 = *(const s16x8*)(ra + ko8);
    s16x8 bhA1 = *(const s16x8*)(ra + 32 + ko8);
    s16x8 blA0 = *(const s16x8*)(la + ko8);
    s16x8 blA1 = *(const s16x8*)(la + 32 + ko8);
    s16x8 bhB0 = *(const s16x8*)(rb + ko8);
    s16x8 bhB1 = *(const s16x8*)(rb + 32 + ko8);
    s16x8 blB0 = *(const s16x8*)(lb + ko8);
    s16x8 blB1 = *(const s16x8*)(lb + 32 + ko8);

    float m1vA = FLT_MAX, m2vA = FLT_MAX; int m1iA = 0;
    float m1vB = FLT_MAX, m2vB = FLT_MAX; int m1iB = 0;
    int sw = (cr & 7) << 4;    // sub-invariant: (cl&7) == (cr&7)

    int cbeg = split * CPS;
    for (int oc = 0; oc < CPS; oc += 64) {
        int cb = cbeg + oc;
        __syncthreads();
        for (int t = tid; t < 512; t += 256) {
            int cc = t >> 3, part = t & 7;
            int bo = (cc * 128 + part * 16) ^ ((cc & 7) << 4);
            *(uint4*)((char*)lah + bo) = *(const uint4*)(embhiN + (size_t)(cb + cc) * 64 + part * 8);
            *(uint4*)((char*)lal + bo) = *(const uint4*)(embloN + (size_t)(cb + cc) * 64 + part * 8);
        }
        if (tid < 64) lq[tid] = hesq[cb + tid];
        __syncthreads();
        #pragma unroll
        for (int sub = 0; sub < 4; ++sub) {
            int rowb = (sub * 16 + cr) * 128;
            s16x8 ah0 = *(const s16x8*)((const char*)lah + ((rowb + ko8 * 2) ^ sw));
            s16x8 ah1 = *(const s16x8*)((const char*)lah + ((rowb + 64 + ko8 * 2) ^ sw));
            s16x8 al0 = *(const s16x8*)((const char*)lal + ((rowb + ko8 * 2) ^ sw));
            s16x8 al1 = *(const s16x8*)((const char*)lal + ((rowb + 64 + ko8 * 2) ^ sw));
            f32x4 q = *(const f32x4*)(lq + sub * 16 + oct * 4);
            int crow = cb + sub * 16 + oct * 4;
            f32x4 acc = q;
            acc = __builtin_amdgcn_mfma_f32_16x16x32_bf16(ah0, bhA0, acc, 0, 0, 0);
            acc = __builtin_amdgcn_mfma_f32_16x16x32_bf16(ah1, bhA1, acc, 0, 0, 0);
            acc = __builtin_amdgcn_mfma_f32_16x16x32_bf16(ah0, blA0, acc, 0, 0, 0);
            acc = __builtin_amdgcn_mfma_f32_16x16x32_bf16(ah1, blA1, acc, 0, 0, 0);
            acc = __builtin_amdgcn_mfma_f32_16x16x32_bf16(al0, bhA0, acc, 0, 0, 0);
            acc = __builtin_amdgcn_mfma_f32_16x16x32_bf16(al1, bhA1, acc, 0, 0, 0);
            #pragma unroll
            for (int r = 0; r < 4; ++r) {
                float s = acc[r];
                bool lt = s < m1vA;
                m2vA = fminf(fmaxf(s, m1vA), m2vA);
                m1iA = lt ? (crow + r) : m1iA;
                m1vA = fminf(s, m1vA);
            }
            f32x4 accB = q;
            accB = __builtin_amdgcn_mfma_f32_16x16x32_bf16(ah0, bhB0, accB, 0, 0, 0);
            accB = __builtin_amdgcn_mfma_f32_16x16x32_bf16(ah1, bhB1, accB, 0, 0, 0);
            accB = __builtin_amdgcn_mfma_f32_16x16x32_bf16(ah0, blB0, accB, 0, 0, 0);
            accB = __builtin_amdgcn_mfma_f32_16x16x32_bf16(ah1, blB1, accB, 0, 0, 0);
            accB = __builtin_amdgcn_mfma_f32_16x16x32_bf16(al0, bhB0, accB, 0, 0, 0);
            accB = __builtin_amdgcn_mfma_f32_16x16x32_bf16(al1, bhB1, accB, 0, 0, 0);
            #pragma unroll
            for (int r = 0; r < 4; ++r) {
                float s = accB[r];
                bool lt = s < m1vB;
                m2vB = fminf(fmaxf(s, m1vB), m2vB);
                m1iB = lt ? (crow + r) : m1iB;
                m1vB = fminf(s, m1vB);
            }
        }
    }
    #pragma unroll
    for (int off = 16; off <= 32; off <<= 1) {
        float o1 = __shfl_xor(m1vA, off, 64); int oi = __shfl_xor(m1iA, off, 64);
        float o2 = __shfl_xor(m2vA, off, 64);
        bool lt = o1 < m1vA;
        m2vA = fminf(fmaxf(o1, m1vA), fminf(m2vA, o2));
        m1vA = fminf(o1, m1vA);
        m1iA = lt ? oi : m1iA;
        o1 = __shfl_xor(m1vB, off, 64); oi = __shfl_xor(m1iB, off, 64);
        o2 = __shfl_xor(m2vB, off, 64);
        lt = o1 < m1vB;
        m2vB = fminf(fmaxf(o1, m1vB), fminf(m2vB, o2));
        m1vB = fminf(o1, m1vB);
        m1iB = lt ? oi : m1iB;
    }
    if (oct == 0) {
        if (ptA < N) { size_t o = (size_t)split * N + ptA; m1v_[o] = m1vA; m1i_[o] = m1iA; m2v_[o] = m2vA; }
        if (ptB < N) { size_t o = (size_t)split * N + ptB; m1v_[o] = m1vB; m1i_[o] = m1iB; m2v_[o] = m2vB; }
    }
}

// merge split partials; init pmin; decide or flag for exact fallback
__global__ void k_vq_combine(const float* __restrict__ m1v_, const int* __restrict__ m1i_,
                             const float* __restrict__ m2v_,
                             int* __restrict__ idx, int* __restrict__ flag, int* __restrict__ count,
                             unsigned long long* __restrict__ pmin, int N, int SPLITS) {
    int n = blockIdx.x * 256 + threadIdx.x;
    if (n >= N) return;
    float a1v = m1v_[n], a2v = m2v_[n];
    int a1i = m1i_[n];
    for (int s = 1; s < SPLITS; ++s) {
        size_t o = (size_t)s * N + n;
        float b1v = m1v_[o], b2v = m2v_[o];
        int b1i = m1i_[o];
        bool lt = b1v < a1v;
        a2v = fminf(fmaxf(b1v, a1v), fminf(a2v, b2v));
        a1v = fminf(b1v, a1v);
        a1i = lt ? b1i : a1i;
    }
    idx[n] = a1i;
    pmin[n] = 0xFFFFFFFFFFFFFFFFull;
    if (a2v - a1v < TAU) {
        int p = atomicAdd(count, 1);
        flag[p] = n;
    }
}

// exact f32 rescan for flagged points (wave-level atomicMin)
__global__ __launch_bounds__(256) void k_vq_exact(
        const float* __restrict__ restnc, const float* __restrict__ embed,
        const float* __restrict__ hesq, const int* __restrict__ flag,
        const int* __restrict__ count, unsigned long long* __restrict__ pmin) {
    __shared__ float rs[32 * 64];
    int tid = threadIdx.x;
    int lane = tid & 63;
    int cnt = *count;
    int nb = (cnt + 31) >> 5;
    int ntask = nb * 16;
    for (int task = blockIdx.x; task < ntask; task += gridDim.x) {
        int batch = task >> 4, spl = task & 15;
        int lbase = batch << 5;
        int npts = min(32, cnt - lbase);
        __syncthreads();
        for (int i = tid; i < npts * 64; i += 256) {
            int li = i >> 6;
            rs[i] = restnc[(size_t)flag[lbase + li] * 64 + (i & 63)];
        }
        __syncthreads();
        int code = spl * 256 + tid;
        const float4* e4 = (const float4*)(embed + (size_t)code * 64);
        float4 e[16];
        #pragma unroll
        for (int i = 0; i < 16; ++i) e[i] = e4[i];
        float hq = hesq[code];
        for (int p = 0; p < npts; ++p) {
            const float4* r4 = (const float4*)(rs + p * 64);
            float d0 = 0.f, d1 = 0.f, d2 = 0.f, d3 = 0.f;
            #pragma unroll
            for (int i = 0; i < 16; i += 4) {
                float4 e0 = e[i], e1 = e[i + 1], e2 = e[i + 2], e3 = e[i + 3];
                d0 += e0.x * r4[i].x     + e0.y * r4[i].y     + e0.z * r4[i].z     + e0.w * r4[i].w;
                d1 += e1.x * r4[i + 1].x + e1.y * r4[i + 1].y + e1.z * r4[i + 1].z + e1.w * r4[i + 1].w;
                d2 += e2.x * r4[i + 2].x + e2.y * r4[i + 2].y + e2.z * r4[i + 2].z + e2.w * r4[i + 2].w;
                d3 += e3.x * r4[i + 3].x + e3.y * r4[i + 3].y + e3.z * r4[i + 3].z + e3.w * r4[i + 3].w;
            }
            float s = hq - ((d0 + d1) + (d2 + d3));
            unsigned u = __float_as_uint(s);
            u = (u & 0x80000000u) ? ~u : (u | 0x80000000u);
            unsigned long long pk = (((unsigned long long)u) << 32) | (unsigned)code;
            #pragma unroll
            for (int off = 32; off; off >>= 1) {
                unsigned long long o = __shfl_down(pk, off, 64);
                if (o < pk) pk = o;
            }
            if (lane == 0) atomicMin(pmin + flag[lbase + p], pk);
        }
    }
}

// ---- MFMA 3x3 conv with FUSED gather+bilinear staging, 4-row blocks, 8 waves ----
// grid (32 b, 8 rg), 512 threads: 4 output rows per block; halo 6 rows x 34 cols.
// Phase A: per-halo-pixel code-index + weight resolve. Phase B: gather from embed
// (identity fast path for pn==32), lerp, bf16 hi/lo split -> XOR-swizzled LDS.
// Wave w: co-half (w&1)*32 (2 co-tiles), px-tiles (w>>1)*2 .. +1. 3-term split MFMA;
// blend operand h = hi+lo read back from LDS.
__global__ __launch_bounds__(512) void k_conv_mfma(
        const int* __restrict__ idx, const unsigned long long* __restrict__ pmin,
        const float* __restrict__ embed,
        const unsigned short* __restrict__ wh, const unsigned short* __restrict__ wl,
        const float* __restrict__ bias, const float* __restrict__ f_in,
        float* __restrict__ f_hat, float* __restrict__ vq_part, int pn) {
    __shared__ __align__(16) unsigned short Xh[6 * 34 * 64];
    __shared__ __align__(16) unsigned short Xl[6 * 34 * 64];
    __shared__ int pid[204][4];
    __shared__ float pwt[204][2];
    int b = blockIdx.x, rg = blockIdx.y;
    int y0 = rg * 4;
    int tid = threadIdx.x;
    int lane = tid & 63, wv = tid >> 6;
    int coh = (wv & 1) * 32;       // co half
    int ph  = (wv >> 1) * 2;       // px-tile base
    int cr = lane & 15, oct = lane >> 4;

    // Phase A: resolve bilinear source codes + weights per halo pixel (204 px)
    if (tid < 204) {
        int lr = tid / 34, lc = tid % 34;
        int gy = y0 + lr - 1, gx = lc - 1;
        if (gy >= 0 && gy < 32 && gx >= 0 && gx < 32) {
            if (pn == 32) {
                int n = (b * 32 + gy) * 32 + gx;
                unsigned long long pv = pmin[n];
                int id = (pv != 0xFFFFFFFFFFFFFFFFull) ? (int)(pv & 0xFFFFFFFFull) : idx[n];
                pid[tid][0] = id;
            } else {
                float scale = (float)pn * (1.0f / 32.0f);
                float sy = (gy + 0.5f) * scale - 0.5f;
                float sx = (gx + 0.5f) * scale - 0.5f;
                float fy0 = floorf(sy), fx0 = floorf(sx);
                float wy = sy - fy0, wx = sx - fx0;
                int yy0 = max(0, min(pn - 1, (int)fy0));
                int yy1 = max(0, min(pn - 1, (int)fy0 + 1));
                int xx0 = max(0, min(pn - 1, (int)fx0));
                int xx1 = max(0, min(pn - 1, (int)fx0 + 1));
                int nb_ = b * pn * pn;
                int n00 = nb_ + yy0 * pn + xx0, n01 = nb_ + yy0 * pn + xx1;
                int n10 = nb_ + yy1 * pn + xx0, n11 = nb_ + yy1 * pn + xx1;
                unsigned long long p00 = pmin[n00], p01 = pmin[n01];
                unsigned long long p10 = pmin[n10], p11 = pmin[n11];
                pid[tid][0] = (p00 != 0xFFFFFFFFFFFFFFFFull) ? (int)(p00 & 0xFFFFFFFFull) : idx[n00];
                pid[tid][1] = (p01 != 0xFFFFFFFFFFFFFFFFull) ? (int)(p01 & 0xFFFFFFFFull) : idx[n01];
                pid[tid][2] = (p10 != 0xFFFFFFFFFFFFFFFFull) ? (int)(p10 & 0xFFFFFFFFull) : idx[n10];
                pid[tid][3] = (p11 != 0xFFFFFFFFFFFFFFFFull) ? (int)(p11 & 0xFFFFFFFFull) : idx[n11];
                pwt[tid][0] = wy; pwt[tid][1] = wx;
            }
        } else {
            pid[tid][0] = -1;
        }
    }
    __syncthreads();

    // Phase B: gather + (lerp) + split -> LDS (204 pixels x 8 chunks)
    for (int q = tid; q < 204 * 8; q += 512) {
        int pl = q >> 3, o8 = q & 7;
        int lc = pl % 34;
        int bo = (pl * 128 + o8 * 16) ^ ((lc & 7) << 4);
        uint4 vh = {0, 0, 0, 0}, vl = {0, 0, 0, 0};
        int i00 = pid[pl][0];
        if (i00 >= 0) {
            union { unsigned short u[8]; uint4 v; } oh, ol;
            if (pn == 32) {
                const float4* e00 = (const float4*)(embed + (size_t)i00 * 64 + o8 * 8);
                #pragma unroll
                for (int half = 0; half < 2; ++half) {
                    float4 a00 = e00[half];
                    float vv[4] = {a00.x, a00.y, a00.z, a00.w};
                    #pragma unroll
                    for (int j = 0; j < 4; ++j) {
                        unsigned short h = f2bf(vv[j]);
                        oh.u[half * 4 + j] = h;
                        ol.u[half * 4 + j] = f2bf(vv[j] - bf2f(h));
                    }
                }
            } else {
                int i01 = pid[pl][1], i10 = pid[pl][2], i11 = pid[pl][3];
                float wy = pwt[pl][0], wx = pwt[pl][1];
                const float4* e00 = (const float4*)(embed + (size_t)i00 * 64 + o8 * 8);
                const float4* e01 = (const float4*)(embed + (size_t)i01 * 64 + o8 * 8);
                const float4* e10 = (const float4*)(embed + (size_t)i10 * 64 + o8 * 8);
                const float4* e11 = (const float4*)(embed + (size_t)i11 * 64 + o8 * 8);
                #pragma unroll
                for (int half = 0; half < 2; ++half) {
                    float4 a00 = e00[half], a01 = e01[half], a10 = e10[half], a11 = e11[half];
                    float t0, t1, vv[4];
                    t0 = a00.x + wx * (a01.x - a00.x); t1 = a10.x + wx * (a11.x - a10.x); vv[0] = t0 + wy * (t1 - t0);
                    t0 = a00.y + wx * (a01.y - a00.y); t1 = a10.y + wx * (a11.y - a10.y); vv[1] = t0 + wy * (t1 - t0);
                    t0 = a00.z + wx * (a01.z - a00.z); t1 = a10.z + wx * (a11.z - a10.z); vv[2] = t0 + wy * (t1 - t0);
                    t0 = a00.w + wx * (a01.w - a00.w); t1 = a10.w + wx * (a11.w - a10.w); vv[3] = t0 + wy * (t1 - t0);
                    #pragma unroll
                    for (int j = 0; j < 4; ++j) {
                        unsigned short h = f2bf(vv[j]);
                        oh.u[half * 4 + j] = h;
                        ol.u[half * 4 + j] = f2bf(vv[j] - bf2f(h));
                    }
                }
            }
            vh = oh.v; vl = ol.v;
        }
        *(uint4*)((char*)Xh + bo) = vh;
        *(uint4*)((char*)Xl + bo) = vl;
    }
    __syncthreads();

    f32x4 acc[2][2];
    #pragma unroll
    for (int ct = 0; ct < 2; ++ct)
        #pragma unroll
        for (int pp = 0; pp < 2; ++pp) acc[ct][pp] = (f32x4){0.f, 0.f, 0.f, 0.f};

    for (int t = 0; t < 9; ++t) {
        int dy = t / 3, dx = t % 3;
        #pragma unroll
        for (int cc = 0; cc < 2; ++cc) {
            size_t wo0 = ((size_t)t * 64 + coh + cr) * 64 + cc * 32 + oct * 8;
            size_t wo1 = ((size_t)t * 64 + coh + 16 + cr) * 64 + cc * 32 + oct * 8;
            s16x8 Ah0 = *(const s16x8*)(wh + wo0);
            s16x8 Al0 = *(const s16x8*)(wl + wo0);
            s16x8 Ah1 = *(const s16x8*)(wh + wo1);
            s16x8 Al1 = *(const s16x8*)(wl + wo1);
            #pragma unroll
            for (int pp = 0; pp < 2; ++pp) {
                int px = (ph + pp) * 16 + cr;
                int lr = (px >> 5) + dy;
                int lc = (px & 31) + dx;
                int bo = ((lr * 34 + lc) * 128 + cc * 64 + oct * 16) ^ ((lc & 7) << 4);
                s16x8 Bh = *(const s16x8*)((const char*)Xh + bo);
                s16x8 Bl = *(const s16x8*)((const char*)Xl + bo);
                acc[0][pp] = __builtin_amdgcn_mfma_f32_16x16x32_bf16(Ah0, Bh, acc[0][pp], 0, 0, 0);
                acc[0][pp] = __builtin_amdgcn_mfma_f32_16x16x32_bf16(Ah0, Bl, acc[0][pp], 0, 0, 0);
                acc[0][pp] = __builtin_amdgcn_mfma_f32_16x16x32_bf16(Al0, Bh, acc[0][pp], 0, 0, 0);
                acc[1][pp] = __builtin_amdgcn_mfma_f32_16x16x32_bf16(Ah1, Bh, acc[1][pp], 0, 0, 0);
                acc[1][pp] = __builtin_amdgcn_mfma_f32_16x16x32_bf16(Ah1, Bl, acc[1][pp], 0, 0, 0);
                acc[1][pp] = __builtin_amdgcn_mfma_f32_16x16x32_bf16(Al1, Bh, acc[1][pp], 0, 0, 0);
            }
        }
    }

    // epilogue: D row (co-in-tile) = oct*4 + r, D col (px-in-tile) = cr
    float local = 0.f;
    #pragma unroll
    for (int ct = 0; ct < 2; ++ct) {
        int cbase = coh + ct * 16 + oct * 4;
        #pragma unroll
        for (int pp = 0; pp < 2; ++pp) {
            int px = (ph + pp) * 16 + cr;
            int y = y0 + (px >> 5), x = px & 31;
            int lr = (px >> 5) + 1, lc = (px & 31) + 1;
            int bo = ((lr * 34 + lc) * 128 + cbase * 2) ^ ((lc & 7) << 4);
            ushort4 hvh = *(const ushort4*)((const char*)Xh + bo);
            ushort4 hvl = *(const ushort4*)((const char*)Xl + bo);
            #pragma unroll
            for (int r = 0; r < 4; ++r) {
                int co = cbase + r;
                unsigned short uh = (r == 0) ? hvh.x : (r == 1) ? hvh.y : (r == 2) ? hvh.z : hvh.w;
                unsigned short ul = (r == 0) ? hvl.x : (r == 1) ? hvl.y : (r == 2) ? hvl.z : hvl.w;
                float hv = bf2f(uh) + bf2f(ul);
                float hconv = acc[ct][pp][r] + bias[co];
                float hout = 0.5f * hv + 0.5f * hconv;
                size_t o = (((size_t)(b * 64 + co)) * 32 + y) * 32 + x;
                float fh = f_hat[o] + hout;
                f_hat[o] = fh;
                float d = fh - f_in[o];
                local += d * d;
            }
        }
    }
    local = blockReduceSum(local);
    if (tid == 0) vq_part[b * 8 + rg] = local;
}

// final: vq losses from vqp (6x256), commit from cmpP (per-scale slot counts) + vq5 identity
__global__ void k_final(const float* __restrict__ vqp, const float* __restrict__ cmpP,
                        float* __restrict__ out) {
    const int pn2s[5] = {1, 4, 16, 64, 256};
    const int slots[5] = {2048, 2048, 2048, 2048, 512};
    __shared__ float commit_s;
    if (threadIdx.x == 0) commit_s = 0.f;
    __syncthreads();
    for (int si = 0; si < 6; ++si) {
        float l = vqp[si * 256 + threadIdx.x];
        l = blockReduceSum(l);
        if (threadIdx.x == 0) {
            float vl = l / (float)N_ELEM;
            out[N_ELEM + si] = vl;
            if (si == 5) commit_s += vl * 0.25f;   // commit(si=5) == vq loss 5
        }
        if (si < 5) {
            float csum = 0.f;
            for (int i = threadIdx.x; i < slots[si]; i += 256) csum += cmpP[si * 2048 + i];
            csum = blockReduceSum(csum);
            if (threadIdx.x == 0) commit_s += csum / (float)(2048 * pn2s[si]) * 0.25f;
        }
    }
    __syncthreads();
    if (threadIdx.x == 0) out[N_ELEM + 6] = commit_s / 6.0f;
}

extern "C" void kernel_launch(void* const* d_in, const int* in_sizes, int n_in,
                              void* d_out, int out_size, void* d_ws, size_t ws_size,
                              hipStream_t stream) {
    const float* f     = (const float*)d_in[0];
    const float* embed = (const float*)d_in[1];
    const float* convw = (const float*)d_in[2];
    const float* convb = (const float*)d_in[3];
    const float* fcw   = (const float*)d_in[4];
    const float* fcb   = (const float*)d_in[5];
    float* out = (float*)d_out;        // f_hat lives in out[0..N_ELEM)
    float* ws  = (float*)d_ws;

    float* restnc = ws + 2097152;                               // 2097152
    unsigned short* resthi = (unsigned short*)(ws + 4194304);   // 2M u16
    unsigned short* restlo = (unsigned short*)(ws + 5242880);   // 2M u16
    unsigned short* embhiN = (unsigned short*)(ws + 6291456);   // 262144 u16
    unsigned short* embloN = (unsigned short*)(ws + 6422528);   // 262144 u16
    unsigned short* wmodh  = (unsigned short*)(ws + 6553600);   // 147456 u16
    unsigned short* wmodl  = (unsigned short*)(ws + 6627328);   // 147456 u16
    float* hesq   = ws + 6701056;                               // 4096
    float* m1v    = ws + 6705152;                               // 262144 (max N*SPL)
    float* m2v    = ws + 6967296;                               // 262144
    int*   m1i    = (int*)(ws + 7229440);                       // 262144
    int*   idx    = (int*)(ws + 7491584);                       // 32768
    int*   flag   = (int*)(ws + 7524352);                       // 32768
    int*   count  = (int*)(ws + 7557120);                       // 64
    unsigned long long* pmin = (unsigned long long*)(ws + 7557184); // 32768 u64
    float* vqp    = ws + 7622720;                               // 1536 (6*256)
    float* cmpP   = ws + 7624256;                               // 10240 (5*2048)

    hipMemsetAsync(d_out, 0, (size_t)out_size * sizeof(float), stream);
    k_wmod<<<576, 256, 0, stream>>>(convw, fcw, fcb, wmodh, wmodl);
    k_embprep<<<16, 256, 0, stream>>>(embed, hesq, embhiN, embloN, count);

    const int pns[6]    = {1, 2, 4, 8, 16, 32};
    const int splits[6] = {64, 64, 64, 64, 16, 8};
    const int kidx[6]   = {0, 0, 1, 2, 3, 3};

    for (int si = 0; si < 6; ++si) {
        int pn = pns[si], pn2 = pn * pn;
        int N = 32 * pn2, SPL = splits[si], CPS = 4096 / SPL;

        // 1. downsample (f - f_hat) -> rest [N][64] f32 + bf16 hi/lo
        if (si <= 4) {
            k_down_plane<<<2048, 256, 0, stream>>>(f, out, restnc, resthi, restlo,
                                                   si >= 1 ? cmpP + (si - 1) * 2048 : nullptr, pn);
        } else {
            k_trans_nc<<<dim3(32, 16), 256, 0, stream>>>(f, out, restnc, resthi, restlo,
                                                         cmpP + 4 * 2048);
        }

        // 2. nearest codebook entry: MFMA approx top-2 -> combine (+pmin init) -> exact fallback
        k_vq_mfma<<<dim3((N + 127) / 128, SPL), 256, 0, stream>>>(resthi, restlo, embhiN, embloN, hesq,
                                                                  m1v, m1i, m2v, N, CPS);
        k_vq_combine<<<(N + 255) / 256, 256, 0, stream>>>(m1v, m1i, m2v, idx, flag, count + si, pmin, N, SPL);
        k_vq_exact<<<512, 256, 0, stream>>>(restnc, embed, hesq, flag, count + si, pmin);

        // 3+4. fused gather/upsample + MFMA Phi conv + blend + f_hat update + vq partials
        k_conv_mfma<<<dim3(32, 8), 512, 0, stream>>>(idx, pmin, embed,
                                                     wmodh + kidx[si] * 36864, wmodl + kidx[si] * 36864,
                                                     convb + kidx[si] * 64, f, out, vqp + si * 256, pn);
    }

    k_final<<<1, 256, 0, stream>>>(vqp, cmpP, out);
}

// Round 14
// 583.503 us; speedup vs baseline: 1.0741x; 1.0062x over previous
//
#include <hip/hip_runtime.h>
#include <cfloat>

// Problem constants: B=32, C=64, H=W=32, V=4096, SN=6, RESI=0.5, BETA=0.25
#define N_ELEM 2097152   // 32*64*32*32
#define TAU 2.0e-2f      // approx-score decision margin (>> worst-case split-bf16 error ~5e-4)

typedef short s16x8 __attribute__((ext_vector_type(8)));
typedef float f32x4 __attribute__((ext_vector_type(4)));

__device__ __forceinline__ unsigned short f2bf(float v) {   // RNE float->bf16 bits
    unsigned u = __float_as_uint(v);
    u += 0x7FFFu + ((u >> 16) & 1u);
    return (unsigned short)(u >> 16);
}
__device__ __forceinline__ float bf2f(unsigned short h) {
    return __uint_as_float(((unsigned)h) << 16);
}

__device__ __forceinline__ float blockReduceSum(float v) {
    __shared__ float red[8];
    #pragma unroll
    for (int off = 32; off; off >>= 1) v += __shfl_down(v, off, 64);
    int wid = threadIdx.x >> 6, lane = threadIdx.x & 63;
    if (lane == 0) red[wid] = v;
    __syncthreads();
    float r = 0.f;
    if (threadIdx.x == 0) {
        int nw = ((int)blockDim.x + 63) >> 6;
        for (int w = 0; w < nw; ++w) r += red[w];
    }
    __syncthreads();
    return r;
}

// fused prep: blocks 0..575 = modulated conv weights -> MFMA layout bf16 hi/lo;
// blocks 576..591 = codebook prep (hesq + NEGATED bf16 hi/lo planes) + count zero.
__global__ void k_prep(const float* __restrict__ w, const float* __restrict__ fcw,
                       const float* __restrict__ fcb,
                       unsigned short* __restrict__ wh, unsigned short* __restrict__ wl,
                       const float* __restrict__ e, float* __restrict__ hesq,
                       unsigned short* __restrict__ ehiN, unsigned short* __restrict__ eloN,
                       int* __restrict__ count) {
    if (blockIdx.x < 576) {
        int i = blockIdx.x * 256 + threadIdx.x;
        int k = i / (64 * 64 * 9);
        int r = i % (64 * 64 * 9);
        int oi = r / 9;            // co*64 + ci
        int t = r % 9;
        int co = oi >> 6, ci = oi & 63;
        float cond = fcw[k * 4096 + oi] * 6.0f + fcb[k * 4096 + oi];
        float v = w[i] * (1.0f + cond);
        size_t o = ((size_t)(k * 9 + t) * 64 + co) * 64 + ci;
        unsigned short h = f2bf(v);
        wh[o] = h;
        wl[o] = f2bf(v - bf2f(h));
        return;
    }
    if (blockIdx.x == 576 && threadIdx.x < 6) count[threadIdx.x] = 0;
    int v = (blockIdx.x - 576) * 256 + threadIdx.x;
    const float4* r = (const float4*)(e + (size_t)v * 64);
    float s = 0.f;
    #pragma unroll
    for (int i = 0; i < 16; ++i) {
        float4 a = r[i];
        s += a.x * a.x + a.y * a.y + a.z * a.z + a.w * a.w;
    }
    hesq[v] = 0.5f * s;
    for (int i = 0; i < 64; ++i) {
        float x = e[(size_t)v * 64 + i];
        unsigned short h = f2bf(x);
        ehiN[(size_t)v * 64 + i] = h ^ 0x8000u;
        eloN[(size_t)v * 64 + i] = f2bf(x - bf2f(h)) ^ 0x8000u;
    }
}

// ---- plane-parallel downsample: one block per (b,c), coalesced reads, LDS reduce ----
__global__ __launch_bounds__(256) void k_down_plane(
        const float* __restrict__ f, const float* __restrict__ fhat,
        float* __restrict__ restnc, unsigned short* __restrict__ dhi,
        unsigned short* __restrict__ dlo, float* __restrict__ cmpPrev, int pn) {
    __shared__ float hs[32][16];   // per-(row, x-pair) partial sums
    __shared__ float cr[32][16];   // per-(row, patch-col) sums
    __shared__ float pm[256];      // patch means (pn*pn <= 256 for pn<=16)
    int bc = blockIdx.x;           // b*64 + c
    int c = bc & 63, b = bc >> 6;
    int t = threadIdx.x;
    const float4* fp = (const float4*)(f + (size_t)bc * 1024);
    const float4* hp = (const float4*)(fhat + (size_t)bc * 1024);
    float4 a = fp[t], q = hp[t];
    int r = t >> 3, c4 = t & 7;
    hs[r][c4 * 2]     = (a.x - q.x) + (a.y - q.y);
    hs[r][c4 * 2 + 1] = (a.z - q.z) + (a.w - q.w);
    __syncthreads();
    int cpp = 16 / pn;             // x-pairs per patch column
    for (int i = t; i < 32 * pn; i += 256) {
        int rr = i / pn, px = i % pn;
        float s = 0.f;
        for (int j = 0; j < cpp; ++j) s += hs[rr][px * cpp + j];
        cr[rr][px] = s;
    }
    __syncthreads();
    int s_ = 32 / pn;
    float inv = 1.0f / (float)(s_ * s_);
    for (int p = t; p < pn * pn; p += 256) {
        int py = p / pn, px = p % pn;
        float s = 0.f;
        for (int j = 0; j < s_; ++j) s += cr[py * s_ + j][px];
        float m = s * inv;
        pm[p] = m;
        int n = (b * pn + py) * pn + px;
        size_t o = (size_t)n * 64 + c;
        unsigned short h = f2bf(m);
        restnc[o] = m;
        dhi[o] = h;
        dlo[o] = f2bf(m - bf2f(h));
    }
    if (pn >= 2) {
        __syncthreads();
        int pnp = pn >> 1;
        float m2 = 0.f;
        for (int p = t; p < pnp * pnp; p += 256) {
            int py = p / pnp, px = p % pnp;
            float mm = 0.25f * (pm[(2 * py) * pn + 2 * px] + pm[(2 * py) * pn + 2 * px + 1]
                              + pm[(2 * py + 1) * pn + 2 * px] + pm[(2 * py + 1) * pn + 2 * px + 1]);
            m2 += mm * mm;
        }
        m2 = blockReduceSum(m2);
        if (t == 0) cmpPrev[blockIdx.x] = m2;
    }
}

// NCHW plane-major [64][1024] per b -> [N][64] f32 + bf16 hi/lo of (f - fhat)  (si=5)
// + fused commit partial for si=4 -> cmp[bx*16 + by] (512 slots).
__global__ void k_trans_nc(const float* __restrict__ A, const float* __restrict__ Bt,
                           float* __restrict__ dst,
                           unsigned short* __restrict__ dhi, unsigned short* __restrict__ dlo,
                           float* __restrict__ cmp) {
    __shared__ float t[64][65];
    int b = blockIdx.x;
    int p0 = blockIdx.y * 64;
    int lane = threadIdx.x & 63, r4 = threadIdx.x >> 6;
    #pragma unroll
    for (int i = 0; i < 16; ++i) {
        int c = i * 4 + r4;
        size_t g = ((size_t)b * 64 + c) * 1024 + p0 + lane;
        t[c][lane] = A[g] - Bt[g];
    }
    __syncthreads();
    #pragma unroll
    for (int i = 0; i < 16; ++i) {
        int p = i * 4 + r4;
        size_t o = ((size_t)(b * 1024 + p0 + p)) * 64 + lane;
        float v = t[lane][p];
        unsigned short h = f2bf(v);
        dst[o] = v;
        dhi[o] = h;
        dlo[o] = f2bf(v - bf2f(h));
    }
    // commit si=4 partial: 64 c x 16 px 2x2-means
    float m2s = 0.f;
    for (int i = threadIdx.x; i < 1024; i += 256) {
        int c = i & 63, px = i >> 6;
        float m = 0.25f * (t[c][2 * px] + t[c][2 * px + 1] + t[c][32 + 2 * px] + t[c][33 + 2 * px]);
        m2s += m * m;
    }
    m2s = blockReduceSum(m2s);
    if (threadIdx.x == 0) cmp[blockIdx.x * 16 + blockIdx.y] = m2s;
}

// ---- MFMA VQ scan: 32 points/wave, negated-code C-init (acc = q - dot),
// fmed3 top-2 (m1<=m2 invariant: new_m2 = median(s,m1,m2), 1 VALU) ----
__global__ __launch_bounds__(256) void k_vq_mfma(
        const unsigned short* __restrict__ resthi, const unsigned short* __restrict__ restlo,
        const unsigned short* __restrict__ embhiN, const unsigned short* __restrict__ embloN,
        const float* __restrict__ hesq,
        float* __restrict__ m1v_, int* __restrict__ m1i_, float* __restrict__ m2v_,
        int N, int CPS) {
    __shared__ __align__(16) unsigned short lah[64 * 64];
    __shared__ __align__(16) unsigned short lal[64 * 64];
    __shared__ __align__(16) float lq[64];
    int tid = threadIdx.x;
    int lane = tid & 63, wv = tid >> 6;
    int split = blockIdx.y;
    int p0 = blockIdx.x * 128 + wv * 32;
    int cr = lane & 15, oct = lane >> 4;
    int ko8 = oct * 8;
    int ptA = p0 + cr, ptB = p0 + 16 + cr;
    int pA = min(ptA, N - 1), pB = min(ptB, N - 1);

    const unsigned short* ra = resthi + (size_t)pA * 64;
    const unsigned short* la = restlo + (size_t)pA * 64;
    const unsigned short* rb = resthi + (size_t)pB * 64;
    const unsigned short* lb = restlo + (size_t)pB * 64;
    s16x8 bhA0 = *(const s16x8*)(ra + ko8);
    s16x8 bhA1 = *(const s16x8*)(ra + 32 + ko8);
    s16x8 blA0 = *(const s16x8*)(la + ko8);
    s16x8 blA1 = *(const s16x8*)(la + 32 + ko8);
    s16x8 bhB0 = *(const s16x8*)(rb + ko8);
    s16x8 bhB1 = *(const s16x8*)(rb + 32 + ko8);
    s16x8 blB0 = *(const s16x8*)(lb + ko8);
    s16x8 blB1 = *(const s16x8*)(lb + 32 + ko8);

    float m1vA = FLT_MAX, m2vA = FLT_MAX; int m1iA = 0;
    float m1vB = FLT_MAX, m2vB = FLT_MAX; int m1iB = 0;
    int sw = (cr & 7) << 4;    // sub-invariant: (cl&7) == (cr&7)

    int cbeg = split * CPS;
    for (int oc = 0; oc < CPS; oc += 64) {
        int cb = cbeg + oc;
        __syncthreads();
        for (int t = tid; t < 512; t += 256) {
            int cc = t >> 3, part = t & 7;
            int bo = (cc * 128 + part * 16) ^ ((cc & 7) << 4);
            *(uint4*)((char*)lah + bo) = *(const uint4*)(embhiN + (size_t)(cb + cc) * 64 + part * 8);
            *(uint4*)((char*)lal + bo) = *(const uint4*)(embloN + (size_t)(cb + cc) * 64 + part * 8);
        }
        if (tid < 64) lq[tid] = hesq[cb + tid];
        __syncthreads();
        #pragma unroll
        for (int sub = 0; sub < 4; ++sub) {
            int rowb = (sub * 16 + cr) * 128;
            s16x8 ah0 = *(const s16x8*)((const char*)lah + ((rowb + ko8 * 2) ^ sw));
            s16x8 ah1 = *(const s16x8*)((const char*)lah + ((rowb + 64 + ko8 * 2) ^ sw));
            s16x8 al0 = *(const s16x8*)((const char*)lal + ((rowb + ko8 * 2) ^ sw));
            s16x8 al1 = *(const s16x8*)((const char*)lal + ((rowb + 64 + ko8 * 2) ^ sw));
            f32x4 q = *(const f32x4*)(lq + sub * 16 + oct * 4);
            int crow = cb + sub * 16 + oct * 4;
            f32x4 acc = q;
            acc = __builtin_amdgcn_mfma_f32_16x16x32_bf16(ah0, bhA0, acc, 0, 0, 0);
            acc = __builtin_amdgcn_mfma_f32_16x16x32_bf16(ah1, bhA1, acc, 0, 0, 0);
            acc = __builtin_amdgcn_mfma_f32_16x16x32_bf16(ah0, blA0, acc, 0, 0, 0);
            acc = __builtin_amdgcn_mfma_f32_16x16x32_bf16(ah1, blA1, acc, 0, 0, 0);
            acc = __builtin_amdgcn_mfma_f32_16x16x32_bf16(al0, bhA0, acc, 0, 0, 0);
            acc = __builtin_amdgcn_mfma_f32_16x16x32_bf16(al1, bhA1, acc, 0, 0, 0);
            #pragma unroll
            for (int r = 0; r < 4; ++r) {
                float s = acc[r];
                bool lt = s < m1vA;
                m2vA = __builtin_amdgcn_fmed3f(s, m1vA, m2vA);
                m1iA = lt ? (crow + r) : m1iA;
                m1vA = fminf(s, m1vA);
            }
            f32x4 accB = q;
            accB = __builtin_amdgcn_mfma_f32_16x16x32_bf16(ah0, bhB0, accB, 0, 0, 0);
            accB = __builtin_amdgcn_mfma_f32_16x16x32_bf16(ah1, bhB1, accB, 0, 0, 0);
            accB = __builtin_amdgcn_mfma_f32_16x16x32_bf16(ah0, blB0, accB, 0, 0, 0);
            accB = __builtin_amdgcn_mfma_f32_16x16x32_bf16(ah1, blB1, accB, 0, 0, 0);
            accB = __builtin_amdgcn_mfma_f32_16x16x32_bf16(al0, bhB0, accB, 0, 0, 0);
            accB = __builtin_amdgcn_mfma_f32_16x16x32_bf16(al1, bhB1, accB, 0, 0, 0);
            #pragma unroll
            for (int r = 0; r < 4; ++r) {
                float s = accB[r];
                bool lt = s < m1vB;
                m2vB = __builtin_amdgcn_fmed3f(s, m1vB, m2vB);
                m1iB = lt ? (crow + r) : m1iB;
                m1vB = fminf(s, m1vB);
            }
        }
    }
    #pragma unroll
    for (int off = 16; off <= 32; off <<= 1) {
        float o1 = __shfl_xor(m1vA, off, 64); int oi = __shfl_xor(m1iA, off, 64);
        float o2 = __shfl_xor(m2vA, off, 64);
        bool lt = o1 < m1vA;
        m2vA = fminf(__builtin_amdgcn_fmed3f(o1, m1vA, m2vA), o2);
        m1vA = fminf(o1, m1vA);
        m1iA = lt ? oi : m1iA;
        o1 = __shfl_xor(m1vB, off, 64); oi = __shfl_xor(m1iB, off, 64);
        o2 = __shfl_xor(m2vB, off, 64);
        lt = o1 < m1vB;
        m2vB = fminf(__builtin_amdgcn_fmed3f(o1, m1vB, m2vB), o2);
        m1vB = fminf(o1, m1vB);
        m1iB = lt ? oi : m1iB;
    }
    if (oct == 0) {
        if (ptA < N) { size_t o = (size_t)split * N + ptA; m1v_[o] = m1vA; m1i_[o] = m1iA; m2v_[o] = m2vA; }
        if (ptB < N) { size_t o = (size_t)split * N + ptB; m1v_[o] = m1vB; m1i_[o] = m1iB; m2v_[o] = m2vB; }
    }
}

// merge split partials; init pmin; decide or flag for exact fallback
__global__ void k_vq_combine(const float* __restrict__ m1v_, const int* __restrict__ m1i_,
                             const float* __restrict__ m2v_,
                             int* __restrict__ idx, int* __restrict__ flag, int* __restrict__ count,
                             unsigned long long* __restrict__ pmin, int N, int SPLITS) {
    int n = blockIdx.x * 256 + threadIdx.x;
    if (n >= N) return;
    float a1v = m1v_[n], a2v = m2v_[n];
    int a1i = m1i_[n];
    for (int s = 1; s < SPLITS; ++s) {
        size_t o = (size_t)s * N + n;
        float b1v = m1v_[o], b2v = m2v_[o];
        int b1i = m1i_[o];
        bool lt = b1v < a1v;
        a2v = fminf(__builtin_amdgcn_fmed3f(b1v, a1v, a2v), b2v);
        a1v = fminf(b1v, a1v);
        a1i = lt ? b1i : a1i;
    }
    idx[n] = a1i;
    pmin[n] = 0xFFFFFFFFFFFFFFFFull;
    if (a2v - a1v < TAU) {
        int p = atomicAdd(count, 1);
        flag[p] = n;
    }
}

// exact f32 rescan for flagged points (wave-level atomicMin)
__global__ __launch_bounds__(256) void k_vq_exact(
        const float* __restrict__ restnc, const float* __restrict__ embed,
        const float* __restrict__ hesq, const int* __restrict__ flag,
        const int* __restrict__ count, unsigned long long* __restrict__ pmin) {
    __shared__ float rs[32 * 64];
    int tid = threadIdx.x;
    int lane = tid & 63;
    int cnt = *count;
    int nb = (cnt + 31) >> 5;
    int ntask = nb * 16;
    for (int task = blockIdx.x; task < ntask; task += gridDim.x) {
        int batch = task >> 4, spl = task & 15;
        int lbase = batch << 5;
        int npts = min(32, cnt - lbase);
        __syncthreads();
        for (int i = tid; i < npts * 64; i += 256) {
            int li = i >> 6;
            rs[i] = restnc[(size_t)flag[lbase + li] * 64 + (i & 63)];
        }
        __syncthreads();
        int code = spl * 256 + tid;
        const float4* e4 = (const float4*)(embed + (size_t)code * 64);
        float4 e[16];
        #pragma unroll
        for (int i = 0; i < 16; ++i) e[i] = e4[i];
        float hq = hesq[code];
        for (int p = 0; p < npts; ++p) {
            const float4* r4 = (const float4*)(rs + p * 64);
            float d0 = 0.f, d1 = 0.f, d2 = 0.f, d3 = 0.f;
            #pragma unroll
            for (int i = 0; i < 16; i += 4) {
                float4 e0 = e[i], e1 = e[i + 1], e2 = e[i + 2], e3 = e[i + 3];
                d0 += e0.x * r4[i].x     + e0.y * r4[i].y     + e0.z * r4[i].z     + e0.w * r4[i].w;
                d1 += e1.x * r4[i + 1].x + e1.y * r4[i + 1].y + e1.z * r4[i + 1].z + e1.w * r4[i + 1].w;
                d2 += e2.x * r4[i + 2].x + e2.y * r4[i + 2].y + e2.z * r4[i + 2].z + e2.w * r4[i + 2].w;
                d3 += e3.x * r4[i + 3].x + e3.y * r4[i + 3].y + e3.z * r4[i + 3].z + e3.w * r4[i + 3].w;
            }
            float s = hq - ((d0 + d1) + (d2 + d3));
            unsigned u = __float_as_uint(s);
            u = (u & 0x80000000u) ? ~u : (u | 0x80000000u);
            unsigned long long pk = (((unsigned long long)u) << 32) | (unsigned)code;
            #pragma unroll
            for (int off = 32; off; off >>= 1) {
                unsigned long long o = __shfl_down(pk, off, 64);
                if (o < pk) pk = o;
            }
            if (lane == 0) atomicMin(pmin + flag[lbase + p], pk);
        }
    }
}

// ---- MFMA 3x3 conv with FUSED gather+bilinear staging, 4-row blocks, 8 waves ----
// grid (32 b, 8 rg), 512 threads. acc C-initialized with bias (VQ C-init trick).
__global__ __launch_bounds__(512) void k_conv_mfma(
        const int* __restrict__ idx, const unsigned long long* __restrict__ pmin,
        const float* __restrict__ embed,
        const unsigned short* __restrict__ wh, const unsigned short* __restrict__ wl,
        const float* __restrict__ bias, const float* __restrict__ f_in,
        float* __restrict__ f_hat, float* __restrict__ vq_part, int pn) {
    __shared__ __align__(16) unsigned short Xh[6 * 34 * 64];
    __shared__ __align__(16) unsigned short Xl[6 * 34 * 64];
    __shared__ int pid[204][4];
    __shared__ float pwt[204][2];
    int b = blockIdx.x, rg = blockIdx.y;
    int y0 = rg * 4;
    int tid = threadIdx.x;
    int lane = tid & 63, wv = tid >> 6;
    int coh = (wv & 1) * 32;       // co half
    int ph  = (wv >> 1) * 2;       // px-tile base
    int cr = lane & 15, oct = lane >> 4;

    // Phase A: resolve bilinear source codes + weights per halo pixel (204 px)
    if (tid < 204) {
        int lr = tid / 34, lc = tid % 34;
        int gy = y0 + lr - 1, gx = lc - 1;
        if (gy >= 0 && gy < 32 && gx >= 0 && gx < 32) {
            if (pn == 32) {
                int n = (b * 32 + gy) * 32 + gx;
                unsigned long long pv = pmin[n];
                int id = (pv != 0xFFFFFFFFFFFFFFFFull) ? (int)(pv & 0xFFFFFFFFull) : idx[n];
                pid[tid][0] = id;
            } else {
                float scale = (float)pn * (1.0f / 32.0f);
                float sy = (gy + 0.5f) * scale - 0.5f;
                float sx = (gx + 0.5f) * scale - 0.5f;
                float fy0 = floorf(sy), fx0 = floorf(sx);
                float wy = sy - fy0, wx = sx - fx0;
                int yy0 = max(0, min(pn - 1, (int)fy0));
                int yy1 = max(0, min(pn - 1, (int)fy0 + 1));
                int xx0 = max(0, min(pn - 1, (int)fx0));
                int xx1 = max(0, min(pn - 1, (int)fx0 + 1));
                int nb_ = b * pn * pn;
                int n00 = nb_ + yy0 * pn + xx0, n01 = nb_ + yy0 * pn + xx1;
                int n10 = nb_ + yy1 * pn + xx0, n11 = nb_ + yy1 * pn + xx1;
                unsigned long long p00 = pmin[n00], p01 = pmin[n01];
                unsigned long long p10 = pmin[n10], p11 = pmin[n11];
                pid[tid][0] = (p00 != 0xFFFFFFFFFFFFFFFFull) ? (int)(p00 & 0xFFFFFFFFull) : idx[n00];
                pid[tid][1] = (p01 != 0xFFFFFFFFFFFFFFFFull) ? (int)(p01 & 0xFFFFFFFFull) : idx[n01];
                pid[tid][2] = (p10 != 0xFFFFFFFFFFFFFFFFull) ? (int)(p10 & 0xFFFFFFFFull) : idx[n10];
                pid[tid][3] = (p11 != 0xFFFFFFFFFFFFFFFFull) ? (int)(p11 & 0xFFFFFFFFull) : idx[n11];
                pwt[tid][0] = wy; pwt[tid][1] = wx;
            }
        } else {
            pid[tid][0] = -1;
        }
    }
    __syncthreads();

    // Phase B: gather + (lerp) + split -> LDS (204 pixels x 8 chunks)
    for (int q = tid; q < 204 * 8; q += 512) {
        int pl = q >> 3, o8 = q & 7;
        int lc = pl % 34;
        int bo = (pl * 128 + o8 * 16) ^ ((lc & 7) << 4);
        uint4 vh = {0, 0, 0, 0}, vl = {0, 0, 0, 0};
        int i00 = pid[pl][0];
        if (i00 >= 0) {
            union { unsigned short u[8]; uint4 v; } oh, ol;
            if (pn == 32) {
                const float4* e00 = (const float4*)(embed + (size_t)i00 * 64 + o8 * 8);
                #pragma unroll
                for (int half = 0; half < 2; ++half) {
                    float4 a00 = e00[half];
                    float vv[4] = {a00.x, a00.y, a00.z, a00.w};
                    #pragma unroll
                    for (int j = 0; j < 4; ++j) {
                        unsigned short h = f2bf(vv[j]);
                        oh.u[half * 4 + j] = h;
                        ol.u[half * 4 + j] = f2bf(vv[j] - bf2f(h));
                    }
                }
            } else {
                int i01 = pid[pl][1], i10 = pid[pl][2], i11 = pid[pl][3];
                float wy = pwt[pl][0], wx = pwt[pl][1];
                const float4* e00 = (const float4*)(embed + (size_t)i00 * 64 + o8 * 8);
                const float4* e01 = (const float4*)(embed + (size_t)i01 * 64 + o8 * 8);
                const float4* e10 = (const float4*)(embed + (size_t)i10 * 64 + o8 * 8);
                const float4* e11 = (const float4*)(embed + (size_t)i11 * 64 + o8 * 8);
                #pragma unroll
                for (int half = 0; half < 2; ++half) {
                    float4 a00 = e00[half], a01 = e01[half], a10 = e10[half], a11 = e11[half];
                    float t0, t1, vv[4];
                    t0 = a00.x + wx * (a01.x - a00.x); t1 = a10.x + wx * (a11.x - a10.x); vv[0] = t0 + wy * (t1 - t0);
                    t0 = a00.y + wx * (a01.y - a00.y); t1 = a10.y + wx * (a11.y - a10.y); vv[1] = t0 + wy * (t1 - t0);
                    t0 = a00.z + wx * (a01.z - a00.z); t1 = a10.z + wx * (a11.z - a10.z); vv[2] = t0 + wy * (t1 - t0);
                    t0 = a00.w + wx * (a01.w - a00.w); t1 = a10.w + wx * (a11.w - a10.w); vv[3] = t0 + wy * (t1 - t0);
                    #pragma unroll
                    for (int j = 0; j < 4; ++j) {
                        unsigned short h = f2bf(vv[j]);
                        oh.u[half * 4 + j] = h;
                        ol.u[half * 4 + j] = f2bf(vv[j] - bf2f(h));
                    }
                }
            }
            vh = oh.v; vl = ol.v;
        }
        *(uint4*)((char*)Xh + bo) = vh;
        *(uint4*)((char*)Xl + bo) = vl;
    }
    __syncthreads();

    // acc C-init with bias: acc[ct][pp][r] starts at bias[coh + ct*16 + oct*4 + r]
    f32x4 b0 = *(const f32x4*)(bias + coh + oct * 4);
    f32x4 b1 = *(const f32x4*)(bias + coh + 16 + oct * 4);
    f32x4 acc[2][2];
    #pragma unroll
    for (int pp = 0; pp < 2; ++pp) { acc[0][pp] = b0; acc[1][pp] = b1; }

    for (int t = 0; t < 9; ++t) {
        int dy = t / 3, dx = t % 3;
        #pragma unroll
        for (int cc = 0; cc < 2; ++cc) {
            size_t wo0 = ((size_t)t * 64 + coh + cr) * 64 + cc * 32 + oct * 8;
            size_t wo1 = ((size_t)t * 64 + coh + 16 + cr) * 64 + cc * 32 + oct * 8;
            s16x8 Ah0 = *(const s16x8*)(wh + wo0);
            s16x8 Al0 = *(const s16x8*)(wl + wo0);
            s16x8 Ah1 = *(const s16x8*)(wh + wo1);
            s16x8 Al1 = *(const s16x8*)(wl + wo1);
            #pragma unroll
            for (int pp = 0; pp < 2; ++pp) {
                int px = (ph + pp) * 16 + cr;
                int lr = (px >> 5) + dy;
                int lc = (px & 31) + dx;
                int bo = ((lr * 34 + lc) * 128 + cc * 64 + oct * 16) ^ ((lc & 7) << 4);
                s16x8 Bh = *(const s16x8*)((const char*)Xh + bo);
                s16x8 Bl = *(const s16x8*)((const char*)Xl + bo);
                acc[0][pp] = __builtin_amdgcn_mfma_f32_16x16x32_bf16(Ah0, Bh, acc[0][pp], 0, 0, 0);
                acc[0][pp] = __builtin_amdgcn_mfma_f32_16x16x32_bf16(Ah0, Bl, acc[0][pp], 0, 0, 0);
                acc[0][pp] = __builtin_amdgcn_mfma_f32_16x16x32_bf16(Al0, Bh, acc[0][pp], 0, 0, 0);
                acc[1][pp] = __builtin_amdgcn_mfma_f32_16x16x32_bf16(Ah1, Bh, acc[1][pp], 0, 0, 0);
                acc[1][pp] = __builtin_amdgcn_mfma_f32_16x16x32_bf16(Ah1, Bl, acc[1][pp], 0, 0, 0);
                acc[1][pp] = __builtin_amdgcn_mfma_f32_16x16x32_bf16(Al1, Bh, acc[1][pp], 0, 0, 0);
            }
        }
    }

    // epilogue: D row (co-in-tile) = oct*4 + r, D col (px-in-tile) = cr
    float local = 0.f;
    #pragma unroll
    for (int ct = 0; ct < 2; ++ct) {
        int cbase = coh + ct * 16 + oct * 4;
        #pragma unroll
        for (int pp = 0; pp < 2; ++pp) {
            int px = (ph + pp) * 16 + cr;
            int y = y0 + (px >> 5), x = px & 31;
            int lr = (px >> 5) + 1, lc = (px & 31) + 1;
            int bo = ((lr * 34 + lc) * 128 + cbase * 2) ^ ((lc & 7) << 4);
            ushort4 hvh = *(const ushort4*)((const char*)Xh + bo);
            ushort4 hvl = *(const ushort4*)((const char*)Xl + bo);
            #pragma unroll
            for (int r = 0; r < 4; ++r) {
                int co = cbase + r;
                unsigned short uh = (r == 0) ? hvh.x : (r == 1) ? hvh.y : (r == 2) ? hvh.z : hvh.w;
                unsigned short ul = (r == 0) ? hvl.x : (r == 1) ? hvl.y : (r == 2) ? hvl.z : hvl.w;
                float hv = bf2f(uh) + bf2f(ul);
                float hout = 0.5f * hv + 0.5f * acc[ct][pp][r];
                size_t o = (((size_t)(b * 64 + co)) * 32 + y) * 32 + x;
                float fh = f_hat[o] + hout;
                f_hat[o] = fh;
                float d = fh - f_in[o];
                local += d * d;
            }
        }
    }
    local = blockReduceSum(local);
    if (tid == 0) vq_part[b * 8 + rg] = local;
}

// final: vq losses from vqp (6x256), commit from cmpP (per-scale slot counts) + vq5 identity
__global__ void k_final(const float* __restrict__ vqp, const float* __restrict__ cmpP,
                        float* __restrict__ out) {
    const int pn2s[5] = {1, 4, 16, 64, 256};
    const int slots[5] = {2048, 2048, 2048, 2048, 512};
    __shared__ float commit_s;
    if (threadIdx.x == 0) commit_s = 0.f;
    __syncthreads();
    for (int si = 0; si < 6; ++si) {
        float l = vqp[si * 256 + threadIdx.x];
        l = blockReduceSum(l);
        if (threadIdx.x == 0) {
            float vl = l / (float)N_ELEM;
            out[N_ELEM + si] = vl;
            if (si == 5) commit_s += vl * 0.25f;   // commit(si=5) == vq loss 5
        }
        if (si < 5) {
            float csum = 0.f;
            for (int i = threadIdx.x; i < slots[si]; i += 256) csum += cmpP[si * 2048 + i];
            csum = blockReduceSum(csum);
            if (threadIdx.x == 0) commit_s += csum / (float)(2048 * pn2s[si]) * 0.25f;
        }
    }
    __syncthreads();
    if (threadIdx.x == 0) out[N_ELEM + 6] = commit_s / 6.0f;
}

extern "C" void kernel_launch(void* const* d_in, const int* in_sizes, int n_in,
                              void* d_out, int out_size, void* d_ws, size_t ws_size,
                              hipStream_t stream) {
    const float* f     = (const float*)d_in[0];
    const float* embed = (const float*)d_in[1];
    const float* convw = (const float*)d_in[2];
    const float* convb = (const float*)d_in[3];
    const float* fcw   = (const float*)d_in[4];
    const float* fcb   = (const float*)d_in[5];
    float* out = (float*)d_out;        // f_hat lives in out[0..N_ELEM)
    float* ws  = (float*)d_ws;

    float* restnc = ws + 2097152;                               // 2097152
    unsigned short* resthi = (unsigned short*)(ws + 4194304);   // 2M u16
    unsigned short* restlo = (unsigned short*)(ws + 5242880);   // 2M u16
    unsigned short* embhiN = (unsigned short*)(ws + 6291456);   // 262144 u16
    unsigned short* embloN = (unsigned short*)(ws + 6422528);   // 262144 u16
    unsigned short* wmodh  = (unsigned short*)(ws + 6553600);   // 147456 u16
    unsigned short* wmodl  = (unsigned short*)(ws + 6627328);   // 147456 u16
    float* hesq   = ws + 6701056;                               // 4096
    float* m1v    = ws + 6705152;                               // 262144 (max N*SPL)
    float* m2v    = ws + 6967296;                               // 262144
    int*   m1i    = (int*)(ws + 7229440);                       // 262144
    int*   idx    = (int*)(ws + 7491584);                       // 32768
    int*   flag   = (int*)(ws + 7524352);                       // 32768
    int*   count  = (int*)(ws + 7557120);                       // 64
    unsigned long long* pmin = (unsigned long long*)(ws + 7557184); // 32768 u64
    float* vqp    = ws + 7622720;                               // 1536 (6*256)
    float* cmpP   = ws + 7624256;                               // 10240 (5*2048)

    hipMemsetAsync(d_out, 0, (size_t)out_size * sizeof(float), stream);
    k_prep<<<592, 256, 0, stream>>>(convw, fcw, fcb, wmodh, wmodl,
                                    embed, hesq, embhiN, embloN, count);

    const int pns[6]    = {1, 2, 4, 8, 16, 32};
    const int splits[6] = {64, 64, 64, 64, 16, 4};
    const int kidx[6]   = {0, 0, 1, 2, 3, 3};

    for (int si = 0; si < 6; ++si) {
        int pn = pns[si], pn2 = pn * pn;
        int N = 32 * pn2, SPL = splits[si], CPS = 4096 / SPL;

        // 1. downsample (f - f_hat) -> rest [N][64] f32 + bf16 hi/lo
        if (si <= 4) {
            k_down_plane<<<2048, 256, 0, stream>>>(f, out, restnc, resthi, restlo,
                                                   si >= 1 ? cmpP + (si - 1) * 2048 : nullptr, pn);
        } else {
            k_trans_nc<<<dim3(32, 16), 256, 0, stream>>>(f, out, restnc, resthi, restlo,
                                                         cmpP + 4 * 2048);
        }

        // 2. nearest codebook entry: MFMA approx top-2 -> combine (+pmin init) -> exact fallback
        k_vq_mfma<<<dim3((N + 127) / 128, SPL), 256, 0, stream>>>(resthi, restlo, embhiN, embloN, hesq,
                                                                  m1v, m1i, m2v, N, CPS);
        k_vq_combine<<<(N + 255) / 256, 256, 0, stream>>>(m1v, m1i, m2v, idx, flag, count + si, pmin, N, SPL);
        k_vq_exact<<<512, 256, 0, stream>>>(restnc, embed, hesq, flag, count + si, pmin);

        // 3+4. fused gather/upsample + MFMA Phi conv + blend + f_hat update + vq partials
        k_conv_mfma<<<dim3(32, 8), 512, 0, stream>>>(idx, pmin, embed,
                                                     wmodh + kidx[si] * 36864, wmodl + kidx[si] * 36864,
                                                     convb + kidx[si] * 64, f, out, vqp + si * 256, pn);
    }

    k_final<<<1, 256, 0, stream>>>(vqp, cmpP, out);
}

// Round 17
// 581.246 us; speedup vs baseline: 1.0782x; 1.0039x over previous
//
#include <hip/hip_runtime.h>
#include <cfloat>

// Problem constants: B=32, C=64, H=W=32, V=4096, SN=6, RESI=0.5, BETA=0.25
#define N_ELEM 2097152   // 32*64*32*32
#define TAU 2.0e-2f      // approx-score decision margin (>> worst-case split-bf16 error ~5e-4)

typedef short s16x8 __attribute__((ext_vector_type(8)));
typedef float f32x4 __attribute__((ext_vector_type(4)));

__device__ __forceinline__ unsigned short f2bf(float v) {   // RNE float->bf16 bits
    unsigned u = __float_as_uint(v);
    u += 0x7FFFu + ((u >> 16) & 1u);
    return (unsigned short)(u >> 16);
}
__device__ __forceinline__ float bf2f(unsigned short h) {
    return __uint_as_float(((unsigned)h) << 16);
}

__device__ __forceinline__ float blockReduceSum(float v) {
    __shared__ float red[8];
    #pragma unroll
    for (int off = 32; off; off >>= 1) v += __shfl_down(v, off, 64);
    int wid = threadIdx.x >> 6, lane = threadIdx.x & 63;
    if (lane == 0) red[wid] = v;
    __syncthreads();
    float r = 0.f;
    if (threadIdx.x == 0) {
        int nw = ((int)blockDim.x + 63) >> 6;
        for (int w = 0; w < nw; ++w) r += red[w];
    }
    __syncthreads();
    return r;
}

// fused prep: blocks 0..575 = modulated conv weights -> MFMA layout bf16 hi/lo;
// blocks 576..591 = codebook prep (hesq + NEGATED bf16 hi/lo planes) + count zero.
__global__ void k_prep(const float* __restrict__ w, const float* __restrict__ fcw,
                       const float* __restrict__ fcb,
                       unsigned short* __restrict__ wh, unsigned short* __restrict__ wl,
                       const float* __restrict__ e, float* __restrict__ hesq,
                       unsigned short* __restrict__ ehiN, unsigned short* __restrict__ eloN,
                       int* __restrict__ count) {
    if (blockIdx.x < 576) {
        int i = blockIdx.x * 256 + threadIdx.x;
        int k = i / (64 * 64 * 9);
        int r = i % (64 * 64 * 9);
        int oi = r / 9;            // co*64 + ci
        int t = r % 9;
        int co = oi >> 6, ci = oi & 63;
        float cond = fcw[k * 4096 + oi] * 6.0f + fcb[k * 4096 + oi];
        float v = w[i] * (1.0f + cond);
        size_t o = ((size_t)(k * 9 + t) * 64 + co) * 64 + ci;
        unsigned short h = f2bf(v);
        wh[o] = h;
        wl[o] = f2bf(v - bf2f(h));
        return;
    }
    if (blockIdx.x == 576 && threadIdx.x < 6) count[threadIdx.x] = 0;
    int v = (blockIdx.x - 576) * 256 + threadIdx.x;
    const float4* r = (const float4*)(e + (size_t)v * 64);
    float s = 0.f;
    #pragma unroll
    for (int i = 0; i < 16; ++i) {
        float4 a = r[i];
        s += a.x * a.x + a.y * a.y + a.z * a.z + a.w * a.w;
    }
    hesq[v] = 0.5f * s;
    for (int i = 0; i < 64; ++i) {
        float x = e[(size_t)v * 64 + i];
        unsigned short h = f2bf(x);
        ehiN[(size_t)v * 64 + i] = h ^ 0x8000u;
        eloN[(size_t)v * 64 + i] = f2bf(x - bf2f(h)) ^ 0x8000u;
    }
}

// ---- plane-parallel downsample: one block per (b,c), coalesced reads, LDS reduce ----
__global__ __launch_bounds__(256) void k_down_plane(
        const float* __restrict__ f, const float* __restrict__ fhat,
        float* __restrict__ restnc, unsigned short* __restrict__ dhi,
        unsigned short* __restrict__ dlo, float* __restrict__ cmpPrev, int pn) {
    __shared__ float hs[32][16];   // per-(row, x-pair) partial sums
    __shared__ float cr[32][16];   // per-(row, patch-col) sums
    __shared__ float pm[256];      // patch means (pn*pn <= 256 for pn<=16)
    int bc = blockIdx.x;           // b*64 + c
    int c = bc & 63, b = bc >> 6;
    int t = threadIdx.x;
    const float4* fp = (const float4*)(f + (size_t)bc * 1024);
    const float4* hp = (const float4*)(fhat + (size_t)bc * 1024);
    float4 a = fp[t], q = hp[t];
    int r = t >> 3, c4 = t & 7;
    hs[r][c4 * 2]     = (a.x - q.x) + (a.y - q.y);
    hs[r][c4 * 2 + 1] = (a.z - q.z) + (a.w - q.w);
    __syncthreads();
    int cpp = 16 / pn;             // x-pairs per patch column
    for (int i = t; i < 32 * pn; i += 256) {
        int rr = i / pn, px = i % pn;
        float s = 0.f;
        for (int j = 0; j < cpp; ++j) s += hs[rr][px * cpp + j];
        cr[rr][px] = s;
    }
    __syncthreads();
    int s_ = 32 / pn;
    float inv = 1.0f / (float)(s_ * s_);
    for (int p = t; p < pn * pn; p += 256) {
        int py = p / pn, px = p % pn;
        float s = 0.f;
        for (int j = 0; j < s_; ++j) s += cr[py * s_ + j][px];
        float m = s * inv;
        pm[p] = m;
        int n = (b * pn + py) * pn + px;
        size_t o = (size_t)n * 64 + c;
        unsigned short h = f2bf(m);
        restnc[o] = m;
        dhi[o] = h;
        dlo[o] = f2bf(m - bf2f(h));
    }
    if (pn >= 2) {
        __syncthreads();
        int pnp = pn >> 1;
        float m2 = 0.f;
        for (int p = t; p < pnp * pnp; p += 256) {
            int py = p / pnp, px = p % pnp;
            float mm = 0.25f * (pm[(2 * py) * pn + 2 * px] + pm[(2 * py) * pn + 2 * px + 1]
                              + pm[(2 * py + 1) * pn + 2 * px] + pm[(2 * py + 1) * pn + 2 * px + 1]);
            m2 += mm * mm;
        }
        m2 = blockReduceSum(m2);
        if (t == 0) cmpPrev[blockIdx.x] = m2;
    }
}

// NCHW plane-major [64][1024] per b -> [N][64] f32 + bf16 hi/lo of (f - fhat)  (si=5)
// + fused commit partial for si=4 -> cmp[bx*16 + by] (512 slots).
__global__ void k_trans_nc(const float* __restrict__ A, const float* __restrict__ Bt,
                           float* __restrict__ dst,
                           unsigned short* __restrict__ dhi, unsigned short* __restrict__ dlo,
                           float* __restrict__ cmp) {
    __shared__ float t[64][65];
    int b = blockIdx.x;
    int p0 = blockIdx.y * 64;
    int lane = threadIdx.x & 63, r4 = threadIdx.x >> 6;
    #pragma unroll
    for (int i = 0; i < 16; ++i) {
        int c = i * 4 + r4;
        size_t g = ((size_t)b * 64 + c) * 1024 + p0 + lane;
        t[c][lane] = A[g] - Bt[g];
    }
    __syncthreads();
    #pragma unroll
    for (int i = 0; i < 16; ++i) {
        int p = i * 4 + r4;
        size_t o = ((size_t)(b * 1024 + p0 + p)) * 64 + lane;
        float v = t[lane][p];
        unsigned short h = f2bf(v);
        dst[o] = v;
        dhi[o] = h;
        dlo[o] = f2bf(v - bf2f(h));
    }
    // commit si=4 partial: 64 c x 16 px 2x2-means
    float m2s = 0.f;
    for (int i = threadIdx.x; i < 1024; i += 256) {
        int c = i & 63, px = i >> 6;
        float m = 0.25f * (t[c][2 * px] + t[c][2 * px + 1] + t[c][32 + 2 * px] + t[c][33 + 2 * px]);
        m2s += m * m;
    }
    m2s = blockReduceSum(m2s);
    if (threadIdx.x == 0) cmp[blockIdx.x * 16 + blockIdx.y] = m2s;
}

// ---- MFMA VQ scan: 8 waves x 32 points per block (256 pts) -> staging writes halved.
// negated-code C-init (acc = q - dot), fmed3 top-2 (m1<=m2 invariant) ----
__global__ __launch_bounds__(512) void k_vq_mfma(
        const unsigned short* __restrict__ resthi, const unsigned short* __restrict__ restlo,
        const unsigned short* __restrict__ embhiN, const unsigned short* __restrict__ embloN,
        const float* __restrict__ hesq,
        float* __restrict__ m1v_, int* __restrict__ m1i_, float* __restrict__ m2v_,
        int N, int CPS) {
    __shared__ __align__(16) unsigned short lah[64 * 64];
    __shared__ __align__(16) unsigned short lal[64 * 64];
    __shared__ __align__(16) float lq[64];
    int tid = threadIdx.x;
    int lane = tid & 63, wv = tid >> 6;
    int split = blockIdx.y;
    int p0 = blockIdx.x * 256 + wv * 32;
    int cr = lane & 15, oct = lane >> 4;
    int ko8 = oct * 8;
    int ptA = p0 + cr, ptB = p0 + 16 + cr;
    int pA = min(ptA, N - 1), pB = min(ptB, N - 1);

    const unsigned short* ra = resthi + (size_t)pA * 64;
    const unsigned short* la = restlo + (size_t)pA * 64;
    const unsigned short* rb = resthi + (size_t)pB * 64;
    const unsigned short* lb = restlo + (size_t)pB * 64;
    s16x8 bhA0 = *(const s16x8*)(ra + ko8);
    s16x8 bhA1 = *(const s16x8*)(ra + 32 + ko8);
    s16x8 blA0 = *(const s16x8*)(la + ko8);
    s16x8 blA1 = *(const s16x8*)(la + 32 + ko8);
    s16x8 bhB0 = *(const s16x8*)(rb + ko8);
    s16x8 bhB1 = *(const s16x8*)(rb + 32 + ko8);
    s16x8 blB0 = *(const s16x8*)(lb + ko8);
    s16x8 blB1 = *(const s16x8*)(lb + 32 + ko8);

    float m1vA = FLT_MAX, m2vA = FLT_MAX; int m1iA = 0;
    float m1vB = FLT_MAX, m2vB = FLT_MAX; int m1iB = 0;
    int sw = (cr & 7) << 4;    // sub-invariant: (cl&7) == (cr&7)

    int cbeg = split * CPS;
    for (int oc = 0; oc < CPS; oc += 64) {
        int cb = cbeg + oc;
        __syncthreads();
        {   // 512 chunks over 512 threads: exactly one per thread
            int cc = tid >> 3, part = tid & 7;
            int bo = (cc * 128 + part * 16) ^ ((cc & 7) << 4);
            *(uint4*)((char*)lah + bo) = *(const uint4*)(embhiN + (size_t)(cb + cc) * 64 + part * 8);
            *(uint4*)((char*)lal + bo) = *(const uint4*)(embloN + (size_t)(cb + cc) * 64 + part * 8);
        }
        if (tid < 64) lq[tid] = hesq[cb + tid];
        __syncthreads();
        #pragma unroll
        for (int sub = 0; sub < 4; ++sub) {
            int rowb = (sub * 16 + cr) * 128;
            s16x8 ah0 = *(const s16x8*)((const char*)lah + ((rowb + ko8 * 2) ^ sw));
            s16x8 ah1 = *(const s16x8*)((const char*)lah + ((rowb + 64 + ko8 * 2) ^ sw));
            s16x8 al0 = *(const s16x8*)((const char*)lal + ((rowb + ko8 * 2) ^ sw));
            s16x8 al1 = *(const s16x8*)((const char*)lal + ((rowb + 64 + ko8 * 2) ^ sw));
            f32x4 q = *(const f32x4*)(lq + sub * 16 + oct * 4);
            int crow = cb + sub * 16 + oct * 4;
            f32x4 acc = q;
            acc = __builtin_amdgcn_mfma_f32_16x16x32_bf16(ah0, bhA0, acc, 0, 0, 0);
            acc = __builtin_amdgcn_mfma_f32_16x16x32_bf16(ah1, bhA1, acc, 0, 0, 0);
            acc = __builtin_amdgcn_mfma_f32_16x16x32_bf16(ah0, blA0, acc, 0, 0, 0);
            acc = __builtin_amdgcn_mfma_f32_16x16x32_bf16(ah1, blA1, acc, 0, 0, 0);
            acc = __builtin_amdgcn_mfma_f32_16x16x32_bf16(al0, bhA0, acc, 0, 0, 0);
            acc = __builtin_amdgcn_mfma_f32_16x16x32_bf16(al1, bhA1, acc, 0, 0, 0);
            #pragma unroll
            for (int r = 0; r < 4; ++r) {
                float s = acc[r];
                bool lt = s < m1vA;
                m2vA = __builtin_amdgcn_fmed3f(s, m1vA, m2vA);
                m1iA = lt ? (crow + r) : m1iA;
                m1vA = fminf(s, m1vA);
            }
            f32x4 accB = q;
            accB = __builtin_amdgcn_mfma_f32_16x16x32_bf16(ah0, bhB0, accB, 0, 0, 0);
            accB = __builtin_amdgcn_mfma_f32_16x16x32_bf16(ah1, bhB1, accB, 0, 0, 0);
            accB = __builtin_amdgcn_mfma_f32_16x16x32_bf16(ah0, blB0, accB, 0, 0, 0);
            accB = __builtin_amdgcn_mfma_f32_16x16x32_bf16(ah1, blB1, accB, 0, 0, 0);
            accB = __builtin_amdgcn_mfma_f32_16x16x32_bf16(al0, bhB0, accB, 0, 0, 0);
            accB = __builtin_amdgcn_mfma_f32_16x16x32_bf16(al1, bhB1, accB, 0, 0, 0);
            #pragma unroll
            for (int r = 0; r < 4; ++r) {
                float s = accB[r];
                bool lt = s < m1vB;
                m2vB = __builtin_amdgcn_fmed3f(s, m1vB, m2vB);
                m1iB = lt ? (crow + r) : m1iB;
                m1vB = fminf(s, m1vB);
            }
        }
    }
    #pragma unroll
    for (int off = 16; off <= 32; off <<= 1) {
        float o1 = __shfl_xor(m1vA, off, 64); int oi = __shfl_xor(m1iA, off, 64);
        float o2 = __shfl_xor(m2vA, off, 64);
        bool lt = o1 < m1vA;
        m2vA = fminf(__builtin_amdgcn_fmed3f(o1, m1vA, m2vA), o2);
        m1vA = fminf(o1, m1vA);
        m1iA = lt ? oi : m1iA;
        o1 = __shfl_xor(m1vB, off, 64); oi = __shfl_xor(m1iB, off, 64);
        o2 = __shfl_xor(m2vB, off, 64);
        lt = o1 < m1vB;
        m2vB = fminf(__builtin_amdgcn_fmed3f(o1, m1vB, m2vB), o2);
        m1vB = fminf(o1, m1vB);
        m1iB = lt ? oi : m1iB;
    }
    if (oct == 0) {
        if (ptA < N) { size_t o = (size_t)split * N + ptA; m1v_[o] = m1vA; m1i_[o] = m1iA; m2v_[o] = m2vA; }
        if (ptB < N) { size_t o = (size_t)split * N + ptB; m1v_[o] = m1vB; m1i_[o] = m1iB; m2v_[o] = m2vB; }
    }
}

// merge split partials; init pmin; decide or flag for exact fallback
__global__ void k_vq_combine(const float* __restrict__ m1v_, const int* __restrict__ m1i_,
                             const float* __restrict__ m2v_,
                             int* __restrict__ idx, int* __restrict__ flag, int* __restrict__ count,
                             unsigned long long* __restrict__ pmin, int N, int SPLITS) {
    int n = blockIdx.x * 256 + threadIdx.x;
    if (n >= N) return;
    float a1v = m1v_[n], a2v = m2v_[n];
    int a1i = m1i_[n];
    for (int s = 1; s < SPLITS; ++s) {
        size_t o = (size_t)s * N + n;
        float b1v = m1v_[o], b2v = m2v_[o];
        int b1i = m1i_[o];
        bool lt = b1v < a1v;
        a2v = fminf(__builtin_amdgcn_fmed3f(b1v, a1v, a2v), b2v);
        a1v = fminf(b1v, a1v);
        a1i = lt ? b1i : a1i;
    }
    idx[n] = a1i;
    pmin[n] = 0xFFFFFFFFFFFFFFFFull;
    if (a2v - a1v < TAU) {
        int p = atomicAdd(count, 1);
        flag[p] = n;
    }
}

// exact f32 rescan for flagged points (wave-level atomicMin)
__global__ __launch_bounds__(256) void k_vq_exact(
        const float* __restrict__ restnc, const float* __restrict__ embed,
        const float* __restrict__ hesq, const int* __restrict__ flag,
        const int* __restrict__ count, unsigned long long* __restrict__ pmin) {
    __shared__ float rs[32 * 64];
    int tid = threadIdx.x;
    int lane = tid & 63;
    int cnt = *count;
    int nb = (cnt + 31) >> 5;
    int ntask = nb * 16;
    for (int task = blockIdx.x; task < ntask; task += gridDim.x) {
        int batch = task >> 4, spl = task & 15;
        int lbase = batch << 5;
        int npts = min(32, cnt - lbase);
        __syncthreads();
        for (int i = tid; i < npts * 64; i += 256) {
            int li = i >> 6;
            rs[i] = restnc[(size_t)flag[lbase + li] * 64 + (i & 63)];
        }
        __syncthreads();
        int code = spl * 256 + tid;
        const float4* e4 = (const float4*)(embed + (size_t)code * 64);
        float4 e[16];
        #pragma unroll
        for (int i = 0; i < 16; ++i) e[i] = e4[i];
        float hq = hesq[code];
        for (int p = 0; p < npts; ++p) {
            const float4* r4 = (const float4*)(rs + p * 64);
            float d0 = 0.f, d1 = 0.f, d2 = 0.f, d3 = 0.f;
            #pragma unroll
            for (int i = 0; i < 16; i += 4) {
                float4 e0 = e[i], e1 = e[i + 1], e2 = e[i + 2], e3 = e[i + 3];
                d0 += e0.x * r4[i].x     + e0.y * r4[i].y     + e0.z * r4[i].z     + e0.w * r4[i].w;
                d1 += e1.x * r4[i + 1].x + e1.y * r4[i + 1].y + e1.z * r4[i + 1].z + e1.w * r4[i + 1].w;
                d2 += e2.x * r4[i + 2].x + e2.y * r4[i + 2].y + e2.z * r4[i + 2].z + e2.w * r4[i + 2].w;
                d3 += e3.x * r4[i + 3].x + e3.y * r4[i + 3].y + e3.z * r4[i + 3].z + e3.w * r4[i + 3].w;
            }
            float s = hq - ((d0 + d1) + (d2 + d3));
            unsigned u = __float_as_uint(s);
            u = (u & 0x80000000u) ? ~u : (u | 0x80000000u);
            unsigned long long pk = (((unsigned long long)u) << 32) | (unsigned)code;
            #pragma unroll
            for (int off = 32; off; off >>= 1) {
                unsigned long long o = __shfl_down(pk, off, 64);
                if (o < pk) pk = o;
            }
            if (lane == 0) atomicMin(pmin + flag[lbase + p], pk);
        }
    }
}

// ---- MFMA 3x3 conv with FUSED gather+bilinear staging, 4-row blocks, 8 waves ----
// grid (32 b, 8 rg), 512 threads. acc C-initialized with bias (VQ C-init trick).
__global__ __launch_bounds__(512) void k_conv_mfma(
        const int* __restrict__ idx, const unsigned long long* __restrict__ pmin,
        const float* __restrict__ embed,
        const unsigned short* __restrict__ wh, const unsigned short* __restrict__ wl,
        const float* __restrict__ bias, const float* __restrict__ f_in,
        float* __restrict__ f_hat, float* __restrict__ vq_part, int pn) {
    __shared__ __align__(16) unsigned short Xh[6 * 34 * 64];
    __shared__ __align__(16) unsigned short Xl[6 * 34 * 64];
    __shared__ int pid[204][4];
    __shared__ float pwt[204][2];
    int b = blockIdx.x, rg = blockIdx.y;
    int y0 = rg * 4;
    int tid = threadIdx.x;
    int lane = tid & 63, wv = tid >> 6;
    int coh = (wv & 1) * 32;       // co half
    int ph  = (wv >> 1) * 2;       // px-tile base
    int cr = lane & 15, oct = lane >> 4;

    // Phase A: resolve bilinear source codes + weights per halo pixel (204 px)
    if (tid < 204) {
        int lr = tid / 34, lc = tid % 34;
        int gy = y0 + lr - 1, gx = lc - 1;
        if (gy >= 0 && gy < 32 && gx >= 0 && gx < 32) {
            if (pn == 32) {
                int n = (b * 32 + gy) * 32 + gx;
                unsigned long long pv = pmin[n];
                int id = (pv != 0xFFFFFFFFFFFFFFFFull) ? (int)(pv & 0xFFFFFFFFull) : idx[n];
                pid[tid][0] = id;
            } else {
                float scale = (float)pn * (1.0f / 32.0f);
                float sy = (gy + 0.5f) * scale - 0.5f;
                float sx = (gx + 0.5f) * scale - 0.5f;
                float fy0 = floorf(sy), fx0 = floorf(sx);
                float wy = sy - fy0, wx = sx - fx0;
                int yy0 = max(0, min(pn - 1, (int)fy0));
                int yy1 = max(0, min(pn - 1, (int)fy0 + 1));
                int xx0 = max(0, min(pn - 1, (int)fx0));
                int xx1 = max(0, min(pn - 1, (int)fx0 + 1));
                int nb_ = b * pn * pn;
                int n00 = nb_ + yy0 * pn + xx0, n01 = nb_ + yy0 * pn + xx1;
                int n10 = nb_ + yy1 * pn + xx0, n11 = nb_ + yy1 * pn + xx1;
                unsigned long long p00 = pmin[n00], p01 = pmin[n01];
                unsigned long long p10 = pmin[n10], p11 = pmin[n11];
                pid[tid][0] = (p00 != 0xFFFFFFFFFFFFFFFFull) ? (int)(p00 & 0xFFFFFFFFull) : idx[n00];
                pid[tid][1] = (p01 != 0xFFFFFFFFFFFFFFFFull) ? (int)(p01 & 0xFFFFFFFFull) : idx[n01];
                pid[tid][2] = (p10 != 0xFFFFFFFFFFFFFFFFull) ? (int)(p10 & 0xFFFFFFFFull) : idx[n10];
                pid[tid][3] = (p11 != 0xFFFFFFFFFFFFFFFFull) ? (int)(p11 & 0xFFFFFFFFull) : idx[n11];
                pwt[tid][0] = wy; pwt[tid][1] = wx;
            }
        } else {
            pid[tid][0] = -1;
        }
    }
    __syncthreads();

    // Phase B: gather + (lerp) + split -> LDS (204 pixels x 8 chunks)
    for (int q = tid; q < 204 * 8; q += 512) {
        int pl = q >> 3, o8 = q & 7;
        int lc = pl % 34;
        int bo = (pl * 128 + o8 * 16) ^ ((lc & 7) << 4);
        uint4 vh = {0, 0, 0, 0}, vl = {0, 0, 0, 0};
        int i00 = pid[pl][0];
        if (i00 >= 0) {
            union { unsigned short u[8]; uint4 v; } oh, ol;
            if (pn == 32) {
                const float4* e00 = (const float4*)(embed + (size_t)i00 * 64 + o8 * 8);
                #pragma unroll
                for (int half = 0; half < 2; ++half) {
                    float4 a00 = e00[half];
                    float vv[4] = {a00.x, a00.y, a00.z, a00.w};
                    #pragma unroll
                    for (int j = 0; j < 4; ++j) {
                        unsigned short h = f2bf(vv[j]);
                        oh.u[half * 4 + j] = h;
                        ol.u[half * 4 + j] = f2bf(vv[j] - bf2f(h));
                    }
                }
            } else {
                int i01 = pid[pl][1], i10 = pid[pl][2], i11 = pid[pl][3];
                float wy = pwt[pl][0], wx = pwt[pl][1];
                const float4* e00 = (const float4*)(embed + (size_t)i00 * 64 + o8 * 8);
                const float4* e01 = (const float4*)(embed + (size_t)i01 * 64 + o8 * 8);
                const float4* e10 = (const float4*)(embed + (size_t)i10 * 64 + o8 * 8);
                const float4* e11 = (const float4*)(embed + (size_t)i11 * 64 + o8 * 8);
                #pragma unroll
                for (int half = 0; half < 2; ++half) {
                    float4 a00 = e00[half], a01 = e01[half], a10 = e10[half], a11 = e11[half];
                    float t0, t1, vv[4];
                    t0 = a00.x + wx * (a01.x - a00.x); t1 = a10.x + wx * (a11.x - a10.x); vv[0] = t0 + wy * (t1 - t0);
                    t0 = a00.y + wx * (a01.y - a00.y); t1 = a10.y + wx * (a11.y - a10.y); vv[1] = t0 + wy * (t1 - t0);
                    t0 = a00.z + wx * (a01.z - a00.z); t1 = a10.z + wx * (a11.z - a10.z); vv[2] = t0 + wy * (t1 - t0);
                    t0 = a00.w + wx * (a01.w - a00.w); t1 = a10.w + wx * (a11.w - a10.w); vv[3] = t0 + wy * (t1 - t0);
                    #pragma unroll
                    for (int j = 0; j < 4; ++j) {
                        unsigned short h = f2bf(vv[j]);
                        oh.u[half * 4 + j] = h;
                        ol.u[half * 4 + j] = f2bf(vv[j] - bf2f(h));
                    }
                }
            }
            vh = oh.v; vl = ol.v;
        }
        *(uint4*)((char*)Xh + bo) = vh;
        *(uint4*)((char*)Xl + bo) = vl;
    }
    __syncthreads();

    // acc C-init with bias: acc[ct][pp][r] starts at bias[coh + ct*16 + oct*4 + r]
    f32x4 b0 = *(const f32x4*)(bias + coh + oct * 4);
    f32x4 b1 = *(const f32x4*)(bias + coh + 16 + oct * 4);
    f32x4 acc[2][2];
    #pragma unroll
    for (int pp = 0; pp < 2; ++pp) { acc[0][pp] = b0; acc[1][pp] = b1; }

    for (int t = 0; t < 9; ++t) {
        int dy = t / 3, dx = t % 3;
        #pragma unroll
        for (int cc = 0; cc < 2; ++cc) {
            size_t wo0 = ((size_t)t * 64 + coh + cr) * 64 + cc * 32 + oct * 8;
            size_t wo1 = ((size_t)t * 64 + coh + 16 + cr) * 64 + cc * 32 + oct * 8;
            s16x8 Ah0 = *(const s16x8*)(wh + wo0);
            s16x8 Al0 = *(const s16x8*)(wl + wo0);
            s16x8 Ah1 = *(const s16x8*)(wh + wo1);
            s16x8 Al1 = *(const s16x8*)(wl + wo1);
            #pragma unroll
            for (int pp = 0; pp < 2; ++pp) {
                int px = (ph + pp) * 16 + cr;
                int lr = (px >> 5) + dy;
                int lc = (px & 31) + dx;
                int bo = ((lr * 34 + lc) * 128 + cc * 64 + oct * 16) ^ ((lc & 7) << 4);
                s16x8 Bh = *(const s16x8*)((const char*)Xh + bo);
                s16x8 Bl = *(const s16x8*)((const char*)Xl + bo);
                acc[0][pp] = __builtin_amdgcn_mfma_f32_16x16x32_bf16(Ah0, Bh, acc[0][pp], 0, 0, 0);
                acc[0][pp] = __builtin_amdgcn_mfma_f32_16x16x32_bf16(Ah0, Bl, acc[0][pp], 0, 0, 0);
                acc[0][pp] = __builtin_amdgcn_mfma_f32_16x16x32_bf16(Al0, Bh, acc[0][pp], 0, 0, 0);
                acc[1][pp] = __builtin_amdgcn_mfma_f32_16x16x32_bf16(Ah1, Bh, acc[1][pp], 0, 0, 0);
                acc[1][pp] = __builtin_amdgcn_mfma_f32_16x16x32_bf16(Ah1, Bl, acc[1][pp], 0, 0, 0);
                acc[1][pp] = __builtin_amdgcn_mfma_f32_16x16x32_bf16(Al1, Bh, acc[1][pp], 0, 0, 0);
            }
        }
    }

    // epilogue: D row (co-in-tile) = oct*4 + r, D col (px-in-tile) = cr
    float local = 0.f;
    #pragma unroll
    for (int ct = 0; ct < 2; ++ct) {
        int cbase = coh + ct * 16 + oct * 4;
        #pragma unroll
        for (int pp = 0; pp < 2; ++pp) {
            int px = (ph + pp) * 16 + cr;
            int y = y0 + (px >> 5), x = px & 31;
            int lr = (px >> 5) + 1, lc = (px & 31) + 1;
            int bo = ((lr * 34 + lc) * 128 + cbase * 2) ^ ((lc & 7) << 4);
            ushort4 hvh = *(const ushort4*)((const char*)Xh + bo);
            ushort4 hvl = *(const ushort4*)((const char*)Xl + bo);
            #pragma unroll
            for (int r = 0; r < 4; ++r) {
                int co = cbase + r;
                unsigned short uh = (r == 0) ? hvh.x : (r == 1) ? hvh.y : (r == 2) ? hvh.z : hvh.w;
                unsigned short ul = (r == 0) ? hvl.x : (r == 1) ? hvl.y : (r == 2) ? hvl.z : hvl.w;
                float hv = bf2f(uh) + bf2f(ul);
                float hout = 0.5f * hv + 0.5f * acc[ct][pp][r];
                size_t o = (((size_t)(b * 64 + co)) * 32 + y) * 32 + x;
                float fh = f_hat[o] + hout;
                f_hat[o] = fh;
                float d = fh - f_in[o];
                local += d * d;
            }
        }
    }
    local = blockReduceSum(local);
    if (tid == 0) vq_part[b * 8 + rg] = local;
}

// final: vq losses from vqp (6x256), commit from cmpP (per-scale slot counts) + vq5 identity
__global__ void k_final(const float* __restrict__ vqp, const float* __restrict__ cmpP,
                        float* __restrict__ out) {
    const int pn2s[5] = {1, 4, 16, 64, 256};
    const int slots[5] = {2048, 2048, 2048, 2048, 512};
    __shared__ float commit_s;
    if (threadIdx.x == 0) commit_s = 0.f;
    __syncthreads();
    for (int si = 0; si < 6; ++si) {
        float l = vqp[si * 256 + threadIdx.x];
        l = blockReduceSum(l);
        if (threadIdx.x == 0) {
            float vl = l / (float)N_ELEM;
            out[N_ELEM + si] = vl;
            if (si == 5) commit_s += vl * 0.25f;   // commit(si=5) == vq loss 5
        }
        if (si < 5) {
            float csum = 0.f;
            for (int i = threadIdx.x; i < slots[si]; i += 256) csum += cmpP[si * 2048 + i];
            csum = blockReduceSum(csum);
            if (threadIdx.x == 0) commit_s += csum / (float)(2048 * pn2s[si]) * 0.25f;
        }
    }
    __syncthreads();
    if (threadIdx.x == 0) out[N_ELEM + 6] = commit_s / 6.0f;
}

extern "C" void kernel_launch(void* const* d_in, const int* in_sizes, int n_in,
                              void* d_out, int out_size, void* d_ws, size_t ws_size,
                              hipStream_t stream) {
    const float* f     = (const float*)d_in[0];
    const float* embed = (const float*)d_in[1];
    const float* convw = (const float*)d_in[2];
    const float* convb = (const float*)d_in[3];
    const float* fcw   = (const float*)d_in[4];
    const float* fcb   = (const float*)d_in[5];
    float* out = (float*)d_out;        // f_hat lives in out[0..N_ELEM)
    float* ws  = (float*)d_ws;

    float* restnc = ws + 2097152;                               // 2097152
    unsigned short* resthi = (unsigned short*)(ws + 4194304);   // 2M u16
    unsigned short* restlo = (unsigned short*)(ws + 5242880);   // 2M u16
    unsigned short* embhiN = (unsigned short*)(ws + 6291456);   // 262144 u16
    unsigned short* embloN = (unsigned short*)(ws + 6422528);   // 262144 u16
    unsigned short* wmodh  = (unsigned short*)(ws + 6553600);   // 147456 u16
    unsigned short* wmodl  = (unsigned short*)(ws + 6627328);   // 147456 u16
    float* hesq   = ws + 6701056;                               // 4096
    float* m1v    = ws + 6705152;                               // 262144 (max N*SPL)
    float* m2v    = ws + 6967296;                               // 262144
    int*   m1i    = (int*)(ws + 7229440);                       // 262144
    int*   idx    = (int*)(ws + 7491584);                       // 32768
    int*   flag   = (int*)(ws + 7524352);                       // 32768
    int*   count  = (int*)(ws + 7557120);                       // 64
    unsigned long long* pmin = (unsigned long long*)(ws + 7557184); // 32768 u64
    float* vqp    = ws + 7622720;                               // 1536 (6*256)
    float* cmpP   = ws + 7624256;                               // 10240 (5*2048)

    hipMemsetAsync(d_out, 0, (size_t)out_size * sizeof(float), stream);
    k_prep<<<592, 256, 0, stream>>>(convw, fcw, fcb, wmodh, wmodl,
                                    embed, hesq, embhiN, embloN, count);

    const int pns[6]    = {1, 2, 4, 8, 16, 32};
    const int splits[6] = {64, 64, 64, 64, 16, 4};
    const int kidx[6]   = {0, 0, 1, 2, 3, 3};

    for (int si = 0; si < 6; ++si) {
        int pn = pns[si], pn2 = pn * pn;
        int N = 32 * pn2, SPL = splits[si], CPS = 4096 / SPL;

        // 1. downsample (f - f_hat) -> rest [N][64] f32 + bf16 hi/lo
        if (si <= 4) {
            k_down_plane<<<2048, 256, 0, stream>>>(f, out, restnc, resthi, restlo,
                                                   si >= 1 ? cmpP + (si - 1) * 2048 : nullptr, pn);
        } else {
            k_trans_nc<<<dim3(32, 16), 256, 0, stream>>>(f, out, restnc, resthi, restlo,
                                                         cmpP + 4 * 2048);
        }

        // 2. nearest codebook entry: MFMA approx top-2 -> combine (+pmin init) -> exact fallback
        k_vq_mfma<<<dim3((N + 255) / 256, SPL), 512, 0, stream>>>(resthi, restlo, embhiN, embloN, hesq,
                                                                  m1v, m1i, m2v, N, CPS);
        k_vq_combine<<<(N + 255) / 256, 256, 0, stream>>>(m1v, m1i, m2v, idx, flag, count + si, pmin, N, SPL);
        k_vq_exact<<<512, 256, 0, stream>>>(restnc, embed, hesq, flag, count + si, pmin);

        // 3+4. fused gather/upsample + MFMA Phi conv + blend + f_hat update + vq partials
        k_conv_mfma<<<dim3(32, 8), 512, 0, stream>>>(idx, pmin, embed,
                                                     wmodh + kidx[si] * 36864, wmodl + kidx[si] * 36864,
                                                     convb + kidx[si] * 64, f, out, vqp + si * 256, pn);
    }

    k_final<<<1, 256, 0, stream>>>(vqp, cmpP, out);
}